// Round 15
// baseline (369.506 us; speedup 1.0000x reference)
//
#include <hip/hip_runtime.h>
#include <hip/hip_bf16.h>
#include <math.h>

#define FDIM 128
#define NREL 6

typedef _Float16 half8 __attribute__((ext_vector_type(8)));
typedef _Float16 h16x2 __attribute__((ext_vector_type(2)));
typedef float f32x4 __attribute__((ext_vector_type(4)));

#if __has_builtin(__builtin_amdgcn_fdot2)
#define FDOT2(A, B, C) __builtin_amdgcn_fdot2((A), (B), (C), false)
#else
#define FDOT2(A, B, C) ((float)(A)[0] * (float)(B)[0] + ((float)(A)[1] * (float)(B)[1] + (C)))
#endif

// ---------------- fp16 helpers ----------------------------------------------
static __device__ __forceinline__ unsigned short f2h(float f) {
  union { _Float16 h; unsigned short u; } p; p.h = (_Float16)f; return p.u;
}

// ---------------------------------------------------------------------------
// dtype conversion passes
// ---------------------------------------------------------------------------
__global__ void cvt_x_kernel(const float* __restrict__ x, unsigned short* __restrict__ xh,
                             int n4) {
  int i = blockIdx.x * 256 + threadIdx.x;
  if (i < n4) {
    float4 v = ((const float4*)x)[i];
    union { _Float16 h[4]; uint2 u; } p;
    p.h[0] = (_Float16)v.x; p.h[1] = (_Float16)v.y;
    p.h[2] = (_Float16)v.z; p.h[3] = (_Float16)v.w;
    ((uint2*)xh)[i] = p.u;
  }
}

// Bt_rgcn[n][kk] (n<128, kk<896) = (kk<128 ? root[kk][n] : w[kk-128][n]) as fp16
__global__ void cvt_wr_kernel(const float* __restrict__ root, const float* __restrict__ w,
                              unsigned short* __restrict__ bt) {
  int i = blockIdx.x * 256 + threadIdx.x;
  if (i < 896 * 128) {
    int n = i / 896, kk = i - n * 896;
    float v = (kk < 128) ? root[kk * 128 + n] : w[(long long)(kk - 128) * 128 + n];
    bt[i] = f2h(v);
  }
}

// Bt_qkvs[z][n][kk] = W_z[kk][n] as fp16
struct WPtrs { const float* W[4]; };
__global__ void cvt_wq_kernel(WPtrs wp, unsigned short* __restrict__ bt) {
  int i = blockIdx.x * 256 + threadIdx.x;
  if (i < 4 * 128 * 128) {
    int z = i >> 14;
    int r = i & 16383;
    int n = r >> 7, kk = r & 127;
    bt[i] = f2h(wp.W[z][kk * 128 + n]);
  }
}

// ---------------------------------------------------------------------------
// FUSED GEMM v2 (R14): phase 1 = RGCN K=896, A double-buffered in LDS (1
// barrier/iter), B fragments read DIRECT from L2-resident btR (no Bh, no
// staging barriers). Phase 2 = q/k/v/skip projections, W fragments direct
// from btQ, ZERO barriers after the single hL-ready barrier.
// R13 was barrier-bound: 44 barriers/block, MfmaUtil 6.9%. Now 15 barriers.
// ---------------------------------------------------------------------------
struct GArgs {
  const unsigned short* Ax;    // fp16 [M][128]  (x_h)
  const unsigned short* Aagg;  // fp16 [M][768]
  const unsigned short* BtR;   // fp16 [128(n)][896]
  const unsigned short* BtQ;   // fp16 [4z][128(n)][128]
  const float* biasR;
  const float* bias2[4];       // bq, bk, bv, bsk
  unsigned short* qh; unsigned short* kh; unsigned short* vh; float* sk;
  int M;
};

__launch_bounds__(256)
__global__ void gemm_fused(GArgs g) {
  __shared__ unsigned short Ah[2][64 * 64];  // 2 x 8 KB (A dbuf, swizzled, 8 units/row)
  __shared__ unsigned short hL[64 * 128];    // 16 KB (h tile fp16, swizzled, 16 units/row)
  const int tid = threadIdx.x;
  const int lane = tid & 63;
  const int wid = tid >> 6;
  const int wm = wid >> 1, wn = wid & 1;
  const int lr = lane & 15, lk = lane >> 4;
  const int m0 = blockIdx.x * 64;
  const int M = g.M;

  // ---- A staging (per-iter, double-buffered) ----
  // thread -> (r, c): 512 uint4 units per tile, 2 per thread
#define STAGE_A(BUF, K0)                                                     \
  {                                                                          \
    _Pragma("unroll")                                                        \
    for (int p = 0; p < 2; ++p) {                                            \
      int idx = tid + 256 * p;                                               \
      int r = idx >> 3, c = idx & 7;                                         \
      int row = m0 + r; if (row > M - 1) row = M - 1;                        \
      const unsigned short* srcp =                                           \
          ((K0) < 128) ? (g.Ax + (long long)row * 128 + (K0) + c * 8)        \
                       : (g.Aagg + (long long)row * 768 + ((K0) - 128) + c * 8); \
      uint4 u = *(const uint4*)srcp;                                         \
      ((uint4*)Ah[BUF])[r * 8 + (c ^ (r & 7))] = u;                          \
    }                                                                        \
  }

  // ================= phase 1: h = [x|agg] @ BtR^T + biasR (K=896) ==========
  f32x4 acc[2][4];
#pragma unroll
  for (int a = 0; a < 2; ++a)
#pragma unroll
    for (int b = 0; b < 4; ++b) { acc[a][b][0] = 0.f; acc[a][b][1] = 0.f; acc[a][b][2] = 0.f; acc[a][b][3] = 0.f; }

  STAGE_A(0, 0)
  int cur = 0;
#pragma unroll 1
  for (int it = 0; it < 14; ++it) {
    __syncthreads();   // buf[cur] ready; everyone done reading buf[cur^1]
    if (it + 1 < 14) STAGE_A(cur ^ 1, (it + 1) * 64)
    const int k0 = it * 64;
#pragma unroll
    for (int ks = 0; ks < 2; ++ks) {
      half8 a[2], b[4];
#pragma unroll
      for (int fm = 0; fm < 2; ++fm) {
        int row = wm * 32 + fm * 16 + lr;
        a[fm] = *(const half8*)&((uint4*)Ah[cur])[row * 8 + ((ks * 4 + lk) ^ (row & 7))];
      }
#pragma unroll
      for (int fn = 0; fn < 4; ++fn) {
        int col = wn * 64 + fn * 16 + lr;
        // direct from L2-resident btR; k = k0 + ks*32 + lk*8 (== old staged map)
        b[fn] = *(const half8*)(g.BtR + (long long)col * 896 + k0 + ks * 32 + lk * 8);
      }
#pragma unroll
      for (int fm = 0; fm < 2; ++fm)
#pragma unroll
        for (int fn = 0; fn < 4; ++fn)
          acc[fm][fn] = __builtin_amdgcn_mfma_f32_16x16x32_f16(a[fm], b[fn], acc[fm][fn], 0, 0, 0);
    }
    cur ^= 1;
  }
#undef STAGE_A

  // ---- epilogue 1: h (f32+bias -> fp16) into swizzled hL (16 units/row) ----
#pragma unroll
  for (int fm = 0; fm < 2; ++fm) {
#pragma unroll
    for (int fn = 0; fn < 4; ++fn) {
      int col = wn * 64 + fn * 16 + lr;
      float bv = g.biasR[col];
      int cu = col >> 3, cb = col & 7;
#pragma unroll
      for (int j = 0; j < 4; ++j) {
        int row = wm * 32 + fm * 16 + lk * 4 + j;   // local row 0..63
        float vv = acc[fm][fn][j] + bv;
        hL[row * 128 + ((cu ^ (row & 7)) << 3) + cb] = f2h(vv);
      }
    }
  }
  __syncthreads();   // hL complete; phase 2 is barrier-free from here

  // ================= phase 2: projections (wave z, K=128) ===================
  const float CF = 0.08838834764831845f * 1.4426950408889634f;  // 1/sqrt(128)*log2(e)
  const float* b2 = (wid == 0) ? g.bias2[0]
                  : (wid == 1) ? g.bias2[1]
                  : (wid == 2) ? g.bias2[2] : g.bias2[3];
  const unsigned short* Wz = g.BtQ + (long long)wid * 16384;
#pragma unroll
  for (int half = 0; half < 2; ++half) {
    f32x4 acc2[4][4];
#pragma unroll
    for (int a = 0; a < 4; ++a)
#pragma unroll
      for (int b = 0; b < 4; ++b) { acc2[a][b][0] = 0.f; acc2[a][b][1] = 0.f; acc2[a][b][2] = 0.f; acc2[a][b][3] = 0.f; }

#pragma unroll
    for (int ks = 0; ks < 4; ++ks) {    // K=128, BK=32
      half8 a[4], b[4];
#pragma unroll
      for (int fm = 0; fm < 4; ++fm) {
        int row = fm * 16 + lr;
        a[fm] = *(const half8*)&((uint4*)hL)[row * 16 + ((ks * 4 + lk) ^ (row & 7))];
      }
#pragma unroll
      for (int fn = 0; fn < 4; ++fn) {
        int n = half * 64 + fn * 16 + lr;
        // direct from L2-resident btQ; k = ks*32 + lk*8
        b[fn] = *(const half8*)(Wz + (long long)n * 128 + ks * 32 + lk * 8);
      }
#pragma unroll
      for (int fm = 0; fm < 4; ++fm)
#pragma unroll
        for (int fn = 0; fn < 4; ++fn)
          acc2[fm][fn] = __builtin_amdgcn_mfma_f32_16x16x32_f16(a[fm], b[fn], acc2[fm][fn], 0, 0, 0);
    }

    // ---- epilogue 2 ----
#pragma unroll
    for (int fm = 0; fm < 4; ++fm) {
#pragma unroll
      for (int fn = 0; fn < 4; ++fn) {
        int col = half * 64 + fn * 16 + lr;
        float bv = b2[col];
#pragma unroll
        for (int j = 0; j < 4; ++j) {
          int row = m0 + fm * 16 + lk * 4 + j;
          if (row < M) {
            float vv = acc2[fm][fn][j] + bv;
            long long off = (long long)row * 128 + col;
            if (wid == 0) g.qh[off] = f2h(vv * CF);
            else if (wid == 1) g.kh[off] = f2h(vv);
            else if (wid == 2) g.vh[off] = f2h(vv);
            else g.sk[off] = vv;
          }
        }
      }
    }
  }
}

// ---------------------------------------------------------------------------
// CSR construction over (dst, rel) keys; csrc stores BYTE offsets (src*256).
// ---------------------------------------------------------------------------
__global__ void hist_kernel(const int* __restrict__ dst, const int* __restrict__ etype,
                            int* __restrict__ cnt, int E) {
  int e = blockIdx.x * blockDim.x + threadIdx.x;
  if (e < E) atomicAdd(&cnt[dst[e] * NREL + etype[e]], 1);
}

__launch_bounds__(1024)
__global__ void scan1(const int* __restrict__ deg, int* __restrict__ incl,
                      int* __restrict__ part, int n) {
  __shared__ int sh[1024];
  int tid = threadIdx.x;
  int i = blockIdx.x * 1024 + tid;
  sh[tid] = (i < n) ? deg[i] : 0;
  __syncthreads();
  for (int o = 1; o < 1024; o <<= 1) {
    int t = (tid >= o) ? sh[tid - o] : 0;
    __syncthreads();
    sh[tid] += t;
    __syncthreads();
  }
  if (i < n) incl[i] = sh[tid];
  if (tid == 1023) part[blockIdx.x] = sh[1023];
}

__global__ void scan2(int* part, int nb) {
  int lane = threadIdx.x;  // 64 threads
  int run = 0;
  for (int b0 = 0; b0 < nb; b0 += 64) {
    int i = b0 + lane;
    int orig = (i < nb) ? part[i] : 0;
    int v = orig;
#pragma unroll
    for (int o = 1; o < 64; o <<= 1) {
      int t = __shfl_up(v, o);
      if (lane >= o) v += t;
    }
    if (i < nb) part[i] = run + v - orig;  // exclusive
    run += __shfl(v, 63);
  }
}

__global__ void scan3(const int* __restrict__ incl, const int* __restrict__ part,
                      int* __restrict__ offs, int n) {
  int i = blockIdx.x * blockDim.x + threadIdx.x;
  if (i < n) {
    offs[i + 1] = incl[i] + part[i >> 10];
    if (i == 0) offs[0] = 0;
  }
}

__global__ void scatter_kernel(const int* __restrict__ src, const int* __restrict__ dst,
                               const int* __restrict__ etype, const int* __restrict__ offs6,
                               int* __restrict__ cur, int* __restrict__ csrc, int E) {
  int e = blockIdx.x * blockDim.x + threadIdx.x;
  if (e < E) {
    int key = dst[e] * NREL + etype[e];
    int p = offs6[key] + atomicAdd(&cur[key], 1);
    csrc[p] = src[e] << 8;   // byte offset into 256-B rows
  }
}

// ---------------------------------------------------------------------------
// RGCN aggregation, one WAVE per node, rel-sorted edges, PREFIX SNAPSHOT.
// 16-deep unrolled gather loop (16 loads in flight; gather-latency-bound).
// ---------------------------------------------------------------------------
__launch_bounds__(256)
__global__ void rgcn_agg(const unsigned short* __restrict__ xh, const int* __restrict__ offs6,
                         const int* __restrict__ csrc,
                         unsigned short* __restrict__ aggh, int N) {
  int node = blockIdx.x * 4 + (threadIdx.x >> 6);
  if (node >= N) return;
  int lane = threadIdx.x & 63;
  const char* xc = (const char*)xh;
  const int* bp = offs6 + node * NREL;
  const int b0 = bp[0];
  int bn0 = bp[1], bn1 = bp[2], bn2 = bp[3], bn3 = bp[4], bn4 = bp[5], bn5 = bp[6];
  const int b6 = bn5;
  unsigned* ap = (unsigned*)(aggh + (long long)node * (NREL * FDIM)) + lane;

  float tx = 0.f, ty = 0.f;
  float px = 0.f, py = 0.f;
  int bprev = b0, snaps = 0;

#define FLUSH(EPOS)                                                          \
  while (snaps < NREL && bn0 == (EPOS)) {                                    \
    int cnt_ = (EPOS) - bprev;                                               \
    float inv_ = cnt_ ? 1.f / (float)cnt_ : 0.f;                             \
    union { _Float16 h[2]; unsigned u; } pk_;                                \
    pk_.h[0] = (_Float16)((tx - px) * inv_);                                 \
    pk_.h[1] = (_Float16)((ty - py) * inv_);                                 \
    *ap = pk_.u; ap += 64;                                                   \
    px = tx; py = ty; bprev = (EPOS); ++snaps;                               \
    bn0 = bn1; bn1 = bn2; bn2 = bn3; bn3 = bn4; bn4 = bn5;                   \
  }

#define EAT(XU)                                                              \
  {                                                                          \
    union { unsigned u; _Float16 h[2]; } c_; c_.u = (XU);                    \
    tx += (float)c_.h[0]; ty += (float)c_.h[1];                              \
  }

  FLUSH(b0)
  int e = b0;
  for (; e + 16 <= b6; e += 16) {
    unsigned xv[16];
#pragma unroll
    for (int t = 0; t < 16; ++t)
      xv[t] = ((const unsigned*)(xc + csrc[e + t]))[lane];
    EAT(xv[0])  FLUSH(e + 1)   EAT(xv[1])  FLUSH(e + 2)
    EAT(xv[2])  FLUSH(e + 3)   EAT(xv[3])  FLUSH(e + 4)
    EAT(xv[4])  FLUSH(e + 5)   EAT(xv[5])  FLUSH(e + 6)
    EAT(xv[6])  FLUSH(e + 7)   EAT(xv[7])  FLUSH(e + 8)
    EAT(xv[8])  FLUSH(e + 9)   EAT(xv[9])  FLUSH(e + 10)
    EAT(xv[10]) FLUSH(e + 11)  EAT(xv[11]) FLUSH(e + 12)
    EAT(xv[12]) FLUSH(e + 13)  EAT(xv[13]) FLUSH(e + 14)
    EAT(xv[14]) FLUSH(e + 15)  EAT(xv[15]) FLUSH(e + 16)
  }
  for (; e + 4 <= b6; e += 4) {
    unsigned y0 = ((const unsigned*)(xc + csrc[e + 0]))[lane];
    unsigned y1 = ((const unsigned*)(xc + csrc[e + 1]))[lane];
    unsigned y2 = ((const unsigned*)(xc + csrc[e + 2]))[lane];
    unsigned y3 = ((const unsigned*)(xc + csrc[e + 3]))[lane];
    EAT(y0) FLUSH(e + 1) EAT(y1) FLUSH(e + 2)
    EAT(y2) FLUSH(e + 3) EAT(y3) FLUSH(e + 4)
  }
  for (; e < b6; ++e) {
    unsigned xv = ((const unsigned*)(xc + csrc[e]))[lane];
    EAT(xv) FLUSH(e + 1)
  }
#undef EAT
#undef FLUSH
}

// ---------------------------------------------------------------------------
// TransformerConv edge-softmax + fused BN-stats accumulation.
// One WAVE per node, QUAD-edge processing (R11-proven). After the softmax
// the wave holds the FINAL pre-BN value (skip+attn) -> block-reduce in LDS,
// one bucketed atomic per feature per block (32 buckets).
// ---------------------------------------------------------------------------
__launch_bounds__(256)
__global__ void attn_kernel(const unsigned short* __restrict__ qh,
                            const unsigned short* __restrict__ kh,
                            const unsigned short* __restrict__ vh,
                            const int* __restrict__ offs6, const int* __restrict__ csrc,
                            float* __restrict__ out,
                            float* __restrict__ gsumB, float* __restrict__ gsqB, int N) {
  __shared__ float bsum[4][FDIM];
  __shared__ float bsq[4][FDIM];
  int wv = threadIdx.x >> 6;
  int node = blockIdx.x * 4 + wv;
  int lane = threadIdx.x & 63;
  bool active = (node < N);
  int start = 0, end = 0;
  if (active) { start = offs6[node * NREL]; end = offs6[node * NREL + NREL]; }
  int deg = end - start;

  const int g16 = lane >> 4;
  const int f = lane & 15;
  const char* kc = (const char*)kh;
  const char* vc = (const char*)vh;

  union U4 { uint4 u; h16x2 h[4]; };
  U4 qf;
  if (active) qf.u = *(const uint4*)(qh + (long long)node * FDIM + f * 8);

  float m = -INFINITY, den = 0.f, acc0 = 0.f, acc1 = 0.f;

#define LOADQ(E0, S0, S1, S2, S3, KU, V0, V1, V2, V3)                        \
  {                                                                          \
    S0 = csrc[(E0) + (g16 ^ 0)];                                             \
    S1 = csrc[(E0) + (g16 ^ 1)];                                             \
    S2 = csrc[(E0) + (g16 ^ 2)];                                             \
    S3 = csrc[(E0) + (g16 ^ 3)];                                             \
    KU = *(const uint4*)(kc + S0 + f * 16);                                  \
    V0 = ((const unsigned*)(vc + S0))[lane];                                 \
    V1 = ((const unsigned*)(vc + S1))[lane];                                 \
    V2 = ((const unsigned*)(vc + S2))[lane];                                 \
    V3 = ((const unsigned*)(vc + S3))[lane];                                 \
  }

#define PROCESS(KU, V0, V1, V2, V3, MASKED, M0, M1, M2, M3)                  \
  {                                                                          \
    U4 kf; kf.u = KU;                                                        \
    float pd = FDOT2(qf.h[0], kf.h[0], 0.f);                                 \
    pd = FDOT2(qf.h[1], kf.h[1], pd);                                        \
    pd = FDOT2(qf.h[2], kf.h[2], pd);                                        \
    pd = FDOT2(qf.h[3], kf.h[3], pd);                                        \
    pd += __shfl_xor(pd, 1);  pd += __shfl_xor(pd, 2);                       \
    pd += __shfl_xor(pd, 4);  pd += __shfl_xor(pd, 8);                       \
    float sc0 = pd;                                                          \
    float sc1 = __shfl_xor(pd, 16);                                          \
    float sc2 = __shfl_xor(pd, 32);                                          \
    float sc3 = __shfl_xor(pd, 48);                                          \
    if (MASKED) {                                                            \
      if (!(M0)) sc0 = -INFINITY;                                            \
      if (!(M1)) sc1 = -INFINITY;                                            \
      if (!(M2)) sc2 = -INFINITY;                                            \
      if (!(M3)) sc3 = -INFINITY;                                            \
    }                                                                        \
    float mx = fmaxf(fmaxf(sc0, sc1), fmaxf(sc2, sc3));                      \
    float mn = fmaxf(m, mx);                                                 \
    float scl = exp2f(m - mn);                                               \
    float a0 = exp2f(sc0 - mn), a1 = exp2f(sc1 - mn);                        \
    float a2 = exp2f(sc2 - mn), a3 = exp2f(sc3 - mn);                        \
    den = den * scl + ((a0 + a1) + (a2 + a3));                               \
    union { unsigned u; _Float16 h[2]; } w0, w1, w2, w3;                     \
    w0.u = V0; w1.u = V1; w2.u = V2; w3.u = V3;                              \
    acc0 = acc0 * scl + a0 * (float)w0.h[0] + a1 * (float)w1.h[0]            \
                      + a2 * (float)w2.h[0] + a3 * (float)w3.h[0];           \
    acc1 = acc1 * scl + a0 * (float)w0.h[1] + a1 * (float)w1.h[1]            \
                      + a2 * (float)w2.h[1] + a3 * (float)w3.h[1];           \
    m = mn;                                                                  \
  }

  if (deg > 0) {
    int nfull4 = deg & ~3;
    int e = start;
    if (nfull4 > 0) {
      int sA0, sA1, sA2, sA3; uint4 kA; unsigned vA0, vA1, vA2, vA3;
      LOADQ(e, sA0, sA1, sA2, sA3, kA, vA0, vA1, vA2, vA3)
      for (; e < start + nfull4; e += 4) {
        int sB0, sB1, sB2, sB3; uint4 kB; unsigned vB0, vB1, vB2, vB3;
        bool more = (e + 4 < start + nfull4);
        if (more) LOADQ(e + 4, sB0, sB1, sB2, sB3, kB, vB0, vB1, vB2, vB3)
        PROCESS(kA, vA0, vA1, vA2, vA3, false, 1, 1, 1, 1)
        if (more) { kA = kB; vA0 = vB0; vA1 = vB1; vA2 = vB2; vA3 = vB3; }
      }
    }
    int rem = deg & 3;
    if (rem) {
      int e0 = start + nfull4;
      int j0 = g16 ^ 0, j1 = g16 ^ 1, j2 = g16 ^ 2, j3 = g16 ^ 3;
      int sT0 = csrc[e0 + (j0 < rem ? j0 : 0)];
      int sT1 = csrc[e0 + (j1 < rem ? j1 : 0)];
      int sT2 = csrc[e0 + (j2 < rem ? j2 : 0)];
      int sT3 = csrc[e0 + (j3 < rem ? j3 : 0)];
      uint4 kT = *(const uint4*)(kc + sT0 + f * 16);
      unsigned vT0 = ((const unsigned*)(vc + sT0))[lane];
      unsigned vT1 = ((const unsigned*)(vc + sT1))[lane];
      unsigned vT2 = ((const unsigned*)(vc + sT2))[lane];
      unsigned vT3 = ((const unsigned*)(vc + sT3))[lane];
      PROCESS(kT, vT0, vT1, vT2, vT3, true, j0 < rem, j1 < rem, j2 < rem, j3 < rem)
    }
  }
#undef LOADQ
#undef PROCESS

  float2 o = make_float2(0.f, 0.f);
  if (active) {
    float2* op = (float2*)(out + (long long)node * FDIM);
    o = op[lane];
    if (deg > 0) {
      float inv = 1.f / den;
      o.x += acc0 * inv;
      o.y += acc1 * inv;
      op[lane] = o;
    }
  }

  // ---- fused BN-stats: o is the final pre-BN value of this node ----
  ((float2*)bsum[wv])[lane] = make_float2(o.x, o.y);
  ((float2*)bsq[wv])[lane]  = make_float2(o.x * o.x, o.y * o.y);
  __syncthreads();
  if (threadIdx.x < FDIM) {
    int d = threadIdx.x;
    float s  = bsum[0][d] + bsum[1][d] + bsum[2][d] + bsum[3][d];
    float q2 = bsq[0][d]  + bsq[1][d]  + bsq[2][d]  + bsq[3][d];
    int bucket = blockIdx.x & 31;
    atomicAdd(&gsumB[bucket * FDIM + d], s);
    atomicAdd(&gsqB[bucket * FDIM + d], q2);
  }
}

// ---------------------------------------------------------------------------
// BatchNorm finalize (reduce 32 buckets) + LeakyReLU apply
// ---------------------------------------------------------------------------
__global__ void bn_final(const float* __restrict__ gsumB, const float* __restrict__ gsqB,
                         const float* __restrict__ gamma, const float* __restrict__ beta,
                         float* __restrict__ ss, int N) {
  int d = threadIdx.x;
  if (d < FDIM) {
    float s = 0.f, q = 0.f;
    for (int b = 0; b < 32; ++b) { s += gsumB[b * FDIM + d]; q += gsqB[b * FDIM + d]; }
    float mean = s / (float)N;
    float var = q / (float)N - mean * mean;
    var = fmaxf(var, 0.f);
    float sc = gamma[d] * rsqrtf(var + 1e-5f);
    ss[d] = sc;
    ss[FDIM + d] = beta[d] - mean * sc;
  }
}

__global__ void bn_apply(float* __restrict__ x, const float* __restrict__ ss, long long total4) {
  long long i = (long long)blockIdx.x * blockDim.x + threadIdx.x;
  if (i < total4) {
    int d0 = (int)((i * 4) & (FDIM - 1));
    float4 vv = ((const float4*)x)[i];
    float y0 = ss[d0 + 0] * vv.x + ss[FDIM + d0 + 0];
    float y1 = ss[d0 + 1] * vv.y + ss[FDIM + d0 + 1];
    float y2 = ss[d0 + 2] * vv.z + ss[FDIM + d0 + 2];
    float y3 = ss[d0 + 3] * vv.w + ss[FDIM + d0 + 3];
    vv.x = (y0 > 0.f) ? y0 : 0.01f * y0;
    vv.y = (y1 > 0.f) ? y1 : 0.01f * y1;
    vv.z = (y2 > 0.f) ? y2 : 0.01f * y2;
    vv.w = (y3 > 0.f) ? y3 : 0.01f * y3;
    ((float4*)x)[i] = vv;
  }
}

// ---------------------------------------------------------------------------
// Launcher
// ---------------------------------------------------------------------------
extern "C" void kernel_launch(void* const* d_in, const int* in_sizes, int n_in,
                              void* d_out, int out_size, void* d_ws, size_t ws_size,
                              hipStream_t stream) {
  const float* x         = (const float*)d_in[0];
  const int*   ei        = (const int*)d_in[1];
  const int*   etype     = (const int*)d_in[2];
  const float* rgcn_w    = (const float*)d_in[3];
  const float* rgcn_root = (const float*)d_in[4];
  const float* rgcn_bias = (const float*)d_in[5];
  const float* wq = (const float*)d_in[6];  const float* bq = (const float*)d_in[7];
  const float* wk = (const float*)d_in[8];  const float* bk = (const float*)d_in[9];
  const float* wv = (const float*)d_in[10]; const float* bv = (const float*)d_in[11];
  const float* wsk = (const float*)d_in[12]; const float* bsk = (const float*)d_in[13];
  const float* gamma = (const float*)d_in[14]; const float* beta = (const float*)d_in[15];

  const int N = in_sizes[0] / FDIM;
  const int E = in_sizes[1] / 2;
  const int* src = ei;
  const int* dst = ei + E;
  const int NK = N * NREL;

  // ---- workspace layout ----
  char* base = (char*)d_ws;
  size_t off = 0;
  auto alloc = [&](size_t bytes) -> char* {
    char* p = base + off;
    off += (bytes + 255) & ~(size_t)255;
    return p;
  };
  unsigned short* aggh = (unsigned short*)alloc((size_t)N * (NREL * FDIM) * 2);  // 76.8MB
  // q/k/v (all fp16) reuse the agg region after the fused GEMM consumes it:
  unsigned short* qbuf = aggh;
  unsigned short* kbuf = aggh + (size_t)N * FDIM;
  unsigned short* vbuf = aggh + 2 * (size_t)N * FDIM;
  unsigned short* xh   = (unsigned short*)alloc((size_t)N * FDIM * 2);
  unsigned short* btR  = (unsigned short*)alloc((size_t)896 * 128 * 2);
  unsigned short* btQ  = (unsigned short*)alloc((size_t)4 * 128 * 128 * 2);
  int* cnt6 = (int*)alloc((size_t)2 * NK * 4);
  int* cur  = cnt6 + NK;
  int* offs6 = (int*)alloc((size_t)(NK + 1) * 4);
  int* incl = (int*)alloc((size_t)NK * 4);
  int* part = (int*)alloc((size_t)512 * 4);
  int* csrc = (int*)alloc((size_t)E * 4);
  float* gsumB = (float*)alloc((size_t)32 * FDIM * 4);
  float* gsqB  = (float*)alloc((size_t)32 * FDIM * 4);
  float* ss    = (float*)alloc((size_t)2 * FDIM * 4);

  float* out = (float*)d_out;

  hipMemsetAsync(cnt6, 0, (size_t)2 * NK * sizeof(int), stream);
  hipMemsetAsync(gsumB, 0, (size_t)64 * FDIM * sizeof(float), stream);  // gsumB+gsqB

  // ---- conversions ----
  int n4 = N * FDIM / 4;
  cvt_x_kernel<<<(n4 + 255) / 256, 256, 0, stream>>>(x, xh, n4);
  cvt_wr_kernel<<<(896 * 128 + 255) / 256, 256, 0, stream>>>(rgcn_root, rgcn_w, btR);
  WPtrs wp; wp.W[0] = wq; wp.W[1] = wk; wp.W[2] = wv; wp.W[3] = wsk;
  cvt_wq_kernel<<<(4 * 128 * 128 + 255) / 256, 256, 0, stream>>>(wp, btQ);

  // ---- CSR build over (dst, rel) keys ----
  hist_kernel<<<(E + 255) / 256, 256, 0, stream>>>(dst, etype, cnt6, E);
  int nb = (NK + 1023) / 1024;
  scan1<<<nb, 1024, 0, stream>>>(cnt6, incl, part, NK);
  scan2<<<1, 64, 0, stream>>>(part, nb);
  scan3<<<(NK + 255) / 256, 256, 0, stream>>>(incl, part, offs6, NK);
  scatter_kernel<<<(E + 255) / 256, 256, 0, stream>>>(src, dst, etype, offs6, cur, csrc, E);

  const int nodeBlocks = (N + 3) / 4;
  const int gemmBlocks = (N + 63) / 64;

  // ---- RGCN aggregate-first, then FUSED GEMM (h + q/k/v/skip in one pass) ----
  rgcn_agg<<<nodeBlocks, 256, 0, stream>>>(xh, offs6, csrc, aggh, N);

  GArgs g = {};
  g.Ax = xh; g.Aagg = aggh; g.BtR = btR; g.BtQ = btQ;
  g.biasR = rgcn_bias;
  g.bias2[0] = bq; g.bias2[1] = bk; g.bias2[2] = bv; g.bias2[3] = bsk;
  g.qh = qbuf; g.kh = kbuf; g.vh = vbuf; g.sk = out;
  g.M = N;
  gemm_fused<<<gemmBlocks, 256, 0, stream>>>(g);

  // ---- edge-softmax attention + fused BN-stats ----
  attn_kernel<<<nodeBlocks, 256, 0, stream>>>(qbuf, kbuf, vbuf, offs6, csrc, out,
                                              gsumB, gsqB, N);

  // ---- BatchNorm finalize + apply ----
  bn_final<<<1, 128, 0, stream>>>(gsumB, gsqB, gamma, beta, ss, N);
  long long total4 = (long long)N * FDIM / 4;
  bn_apply<<<(int)((total4 + 255) / 256), 256, 0, stream>>>(out, ss, total4);
}

// Round 16
// 327.854 us; speedup vs baseline: 1.1270x; 1.1270x over previous
//
#include <hip/hip_runtime.h>
#include <hip/hip_bf16.h>
#include <math.h>

#define FDIM 128
#define NREL 6

typedef _Float16 half8 __attribute__((ext_vector_type(8)));
typedef _Float16 h16x2 __attribute__((ext_vector_type(2)));
typedef float f32x4 __attribute__((ext_vector_type(4)));

#if __has_builtin(__builtin_amdgcn_fdot2)
#define FDOT2(A, B, C) __builtin_amdgcn_fdot2((A), (B), (C), false)
#else
#define FDOT2(A, B, C) ((float)(A)[0] * (float)(B)[0] + ((float)(A)[1] * (float)(B)[1] + (C)))
#endif

// ---------------- fp16 helpers ----------------------------------------------
static __device__ __forceinline__ unsigned short f2h(float f) {
  union { _Float16 h; unsigned short u; } p; p.h = (_Float16)f; return p.u;
}

// ---------------------------------------------------------------------------
// dtype conversion passes
// ---------------------------------------------------------------------------
__global__ void cvt_x_kernel(const float* __restrict__ x, unsigned short* __restrict__ xh,
                             int n4) {
  int i = blockIdx.x * 256 + threadIdx.x;
  if (i < n4) {
    float4 v = ((const float4*)x)[i];
    union { _Float16 h[4]; uint2 u; } p;
    p.h[0] = (_Float16)v.x; p.h[1] = (_Float16)v.y;
    p.h[2] = (_Float16)v.z; p.h[3] = (_Float16)v.w;
    ((uint2*)xh)[i] = p.u;
  }
}

// Bt_rgcn[n][kk] (n<128, kk<896) = (kk<128 ? root[kk][n] : w[kk-128][n]) as fp16
__global__ void cvt_wr_kernel(const float* __restrict__ root, const float* __restrict__ w,
                              unsigned short* __restrict__ bt) {
  int i = blockIdx.x * 256 + threadIdx.x;
  if (i < 896 * 128) {
    int n = i / 896, kk = i - n * 896;
    float v = (kk < 128) ? root[kk * 128 + n] : w[(long long)(kk - 128) * 128 + n];
    bt[i] = f2h(v);
  }
}

// Bt_qkvs[z][n][kk] = W_z[kk][n] as fp16
struct WPtrs { const float* W[4]; };
__global__ void cvt_wq_kernel(WPtrs wp, unsigned short* __restrict__ bt) {
  int i = blockIdx.x * 256 + threadIdx.x;
  if (i < 4 * 128 * 128) {
    int z = i >> 14;
    int r = i & 16383;
    int n = r >> 7, kk = r & 127;
    bt[i] = f2h(wp.W[z][kk * 128 + n]);
  }
}

// ---------------------------------------------------------------------------
// FUSED GEMM v3 (R16): R13's verified coalesced LDS staging + addressing, but
// DOUBLE-BUFFERED: phase 1 A(2x8KB)+B(2x16KB) -> 1 barrier/K-step (14 total);
// phase 2 W chunks dbuf reusing Bh -> 8 barriers (first also covers hL).
// R13 = 44 barriers (99us, MfmaUtil 6.9%); R14's direct-global B regressed
// (uncoalesced 64-line fragment loads). Now 22 barriers, staging coalesced.
// ---------------------------------------------------------------------------
struct GArgs {
  const unsigned short* Ax;    // fp16 [M][128]  (x_h)
  const unsigned short* Aagg;  // fp16 [M][768]
  const unsigned short* BtR;   // fp16 [128(n)][896]
  const unsigned short* BtQ;   // fp16 [4z][128(n)][128]
  const float* biasR;
  const float* bias2[4];       // bq, bk, bv, bsk
  unsigned short* qh; unsigned short* kh; unsigned short* vh; float* sk;
  int M;
};

__launch_bounds__(256)
__global__ void gemm_fused(GArgs g) {
  __shared__ unsigned short Ah[2][64 * 64];    // 2 x 8 KB  (A dbuf, swizzled)
  __shared__ unsigned short Bh[2][128 * 64];   // 2 x 16 KB (B dbuf / W dbuf)
  __shared__ unsigned short hL[64 * 128];      // 16 KB (h tile, swizzled, 16 units/row)
  const int tid = threadIdx.x;
  const int lane = tid & 63;
  const int wid = tid >> 6;
  const int wm = wid >> 1, wn = wid & 1;
  const int lr = lane & 15, lk = lane >> 4;
  const int m0 = blockIdx.x * 64;
  const int M = g.M;

#define STAGE_A(BUF, K0)                                                     \
  {                                                                          \
    _Pragma("unroll")                                                        \
    for (int p = 0; p < 2; ++p) {                                            \
      int idx = tid + 256 * p;                                               \
      int r = idx >> 3, c = idx & 7;                                         \
      int row = m0 + r; if (row > M - 1) row = M - 1;                        \
      const unsigned short* srcp =                                           \
          ((K0) < 128) ? (g.Ax + (long long)row * 128 + (K0) + c * 8)        \
                       : (g.Aagg + (long long)row * 768 + ((K0) - 128) + c * 8); \
      uint4 u = *(const uint4*)srcp;                                         \
      ((uint4*)Ah[BUF])[r * 8 + (c ^ (r & 7))] = u;                          \
    }                                                                        \
  }

#define STAGE_B(BUF, K0)                                                     \
  {                                                                          \
    _Pragma("unroll")                                                        \
    for (int p = 0; p < 4; ++p) {                                            \
      int idx = tid + 256 * p;                                               \
      int rn = idx >> 3, c = idx & 7;                                        \
      uint4 u = *(const uint4*)(g.BtR + (long long)rn * 896 + (K0) + c * 8); \
      ((uint4*)Bh[BUF])[rn * 8 + (c ^ (rn & 7))] = u;                        \
    }                                                                        \
  }

#define STAGE_W(BUF, HALF, KS)                                               \
  {                                                                          \
    _Pragma("unroll")                                                        \
    for (int p = 0; p < 4; ++p) {                                            \
      int u_ = tid + 256 * p;                                                \
      int zz = u_ >> 8, n = (u_ >> 2) & 63, c = u_ & 3;                      \
      uint4 w = *(const uint4*)(g.BtQ + (long long)zz * 16384 +              \
                                (long long)((HALF) * 64 + n) * 128 +         \
                                (KS) * 32 + c * 8);                          \
      ((uint4*)Bh[BUF])[zz * 256 + n * 4 + (c ^ (n & 3))] = w;               \
    }                                                                        \
  }

  // ================= phase 1: h = [x|agg] @ BtR^T + biasR (K=896) ==========
  f32x4 acc[2][4];
#pragma unroll
  for (int a = 0; a < 2; ++a)
#pragma unroll
    for (int b = 0; b < 4; ++b) { acc[a][b][0] = 0.f; acc[a][b][1] = 0.f; acc[a][b][2] = 0.f; acc[a][b][3] = 0.f; }

  STAGE_A(0, 0)
  STAGE_B(0, 0)
  int cur = 0;
#pragma unroll 1
  for (int it = 0; it < 14; ++it) {
    __syncthreads();   // buf[cur] ready; all reads of buf[cur^1] retired
    if (it + 1 < 14) {
      STAGE_A(cur ^ 1, (it + 1) * 64)
      STAGE_B(cur ^ 1, (it + 1) * 64)
    }
#pragma unroll
    for (int ks = 0; ks < 2; ++ks) {
      half8 a[2], b[4];
#pragma unroll
      for (int fm = 0; fm < 2; ++fm) {
        int row = wm * 32 + fm * 16 + lr;
        a[fm] = *(const half8*)&((uint4*)Ah[cur])[row * 8 + ((ks * 4 + lk) ^ (row & 7))];
      }
#pragma unroll
      for (int fn = 0; fn < 4; ++fn) {
        int col = wn * 64 + fn * 16 + lr;
        b[fn] = *(const half8*)&((uint4*)Bh[cur])[col * 8 + ((ks * 4 + lk) ^ (col & 7))];
      }
#pragma unroll
      for (int fm = 0; fm < 2; ++fm)
#pragma unroll
        for (int fn = 0; fn < 4; ++fn)
          acc[fm][fn] = __builtin_amdgcn_mfma_f32_16x16x32_f16(a[fm], b[fn], acc[fm][fn], 0, 0, 0);
    }
    cur ^= 1;
  }

  // ---- epilogue 1: h (f32+bias -> fp16) into swizzled hL (16 units/row) ----
  // Each wave writes only its own (wm,wn) region -> no intra-phase hazard.
#pragma unroll
  for (int fm = 0; fm < 2; ++fm) {
#pragma unroll
    for (int fn = 0; fn < 4; ++fn) {
      int col = wn * 64 + fn * 16 + lr;
      float bv = g.biasR[col];
      int cu = col >> 3, cb = col & 7;
#pragma unroll
      for (int j = 0; j < 4; ++j) {
        int row = wm * 32 + fm * 16 + lk * 4 + j;   // local row 0..63
        float vv = acc[fm][fn][j] + bv;
        hL[row * 128 + ((cu ^ (row & 7)) << 3) + cb] = f2h(vv);
      }
    }
  }

  // ================= phase 2: projections (wave z, K=128) ===================
  // W chunk (half, ks) = 16KB staged into Bh[wcur^1] while computing Bh[wcur].
  // Safe vs phase 1: Bh[0] was last READ at it=12; writes race only with
  // it=13's reads of Bh[1]. First loop barrier covers hL + W chunk 0.
  const float CF = 0.08838834764831845f * 1.4426950408889634f;  // 1/sqrt(128)*log2(e)
  const float* b2 = (wid == 0) ? g.bias2[0]
                  : (wid == 1) ? g.bias2[1]
                  : (wid == 2) ? g.bias2[2] : g.bias2[3];
  STAGE_W(0, 0, 0)
  int wcur = 0;
#pragma unroll
  for (int half = 0; half < 2; ++half) {
    f32x4 acc2[4][4];
#pragma unroll
    for (int a = 0; a < 4; ++a)
#pragma unroll
      for (int b = 0; b < 4; ++b) { acc2[a][b][0] = 0.f; acc2[a][b][1] = 0.f; acc2[a][b][2] = 0.f; acc2[a][b][3] = 0.f; }

#pragma unroll
    for (int ks = 0; ks < 4; ++ks) {    // K=128, BK=32
      __syncthreads();   // Bh[wcur] (and hL on first pass) ready
      const int cidx = half * 4 + ks;
      if (cidx + 1 < 8) {
        const int nh = (cidx + 1) >> 2, nk = (cidx + 1) & 3;
        STAGE_W(wcur ^ 1, nh, nk)
      }
      half8 a[4], b[4];
#pragma unroll
      for (int fm = 0; fm < 4; ++fm) {
        int row = fm * 16 + lr;
        a[fm] = *(const half8*)&((uint4*)hL)[row * 16 + ((ks * 4 + lk) ^ (row & 7))];
      }
#pragma unroll
      for (int fn = 0; fn < 4; ++fn) {
        int n = fn * 16 + lr;
        b[fn] = *(const half8*)&((uint4*)Bh[wcur])[wid * 256 + n * 4 + (lk ^ (n & 3))];
      }
#pragma unroll
      for (int fm = 0; fm < 4; ++fm)
#pragma unroll
        for (int fn = 0; fn < 4; ++fn)
          acc2[fm][fn] = __builtin_amdgcn_mfma_f32_16x16x32_f16(a[fm], b[fn], acc2[fm][fn], 0, 0, 0);
      wcur ^= 1;
    }

    // ---- epilogue 2 ----
#pragma unroll
    for (int fm = 0; fm < 4; ++fm) {
#pragma unroll
      for (int fn = 0; fn < 4; ++fn) {
        int col = half * 64 + fn * 16 + lr;
        float bv = b2[col];
#pragma unroll
        for (int j = 0; j < 4; ++j) {
          int row = m0 + fm * 16 + lk * 4 + j;
          if (row < M) {
            float vv = acc2[fm][fn][j] + bv;
            long long off = (long long)row * 128 + col;
            if (wid == 0) g.qh[off] = f2h(vv * CF);
            else if (wid == 1) g.kh[off] = f2h(vv);
            else if (wid == 2) g.vh[off] = f2h(vv);
            else g.sk[off] = vv;
          }
        }
      }
    }
  }
#undef STAGE_A
#undef STAGE_B
#undef STAGE_W
}

// ---------------------------------------------------------------------------
// CSR construction over (dst, rel) keys; csrc stores BYTE offsets (src*256).
// ---------------------------------------------------------------------------
__global__ void hist_kernel(const int* __restrict__ dst, const int* __restrict__ etype,
                            int* __restrict__ cnt, int E) {
  int e = blockIdx.x * blockDim.x + threadIdx.x;
  if (e < E) atomicAdd(&cnt[dst[e] * NREL + etype[e]], 1);
}

__launch_bounds__(1024)
__global__ void scan1(const int* __restrict__ deg, int* __restrict__ incl,
                      int* __restrict__ part, int n) {
  __shared__ int sh[1024];
  int tid = threadIdx.x;
  int i = blockIdx.x * 1024 + tid;
  sh[tid] = (i < n) ? deg[i] : 0;
  __syncthreads();
  for (int o = 1; o < 1024; o <<= 1) {
    int t = (tid >= o) ? sh[tid - o] : 0;
    __syncthreads();
    sh[tid] += t;
    __syncthreads();
  }
  if (i < n) incl[i] = sh[tid];
  if (tid == 1023) part[blockIdx.x] = sh[1023];
}

__global__ void scan2(int* part, int nb) {
  int lane = threadIdx.x;  // 64 threads
  int run = 0;
  for (int b0 = 0; b0 < nb; b0 += 64) {
    int i = b0 + lane;
    int orig = (i < nb) ? part[i] : 0;
    int v = orig;
#pragma unroll
    for (int o = 1; o < 64; o <<= 1) {
      int t = __shfl_up(v, o);
      if (lane >= o) v += t;
    }
    if (i < nb) part[i] = run + v - orig;  // exclusive
    run += __shfl(v, 63);
  }
}

__global__ void scan3(const int* __restrict__ incl, const int* __restrict__ part,
                      int* __restrict__ offs, int n) {
  int i = blockIdx.x * blockDim.x + threadIdx.x;
  if (i < n) {
    offs[i + 1] = incl[i] + part[i >> 10];
    if (i == 0) offs[0] = 0;
  }
}

__global__ void scatter_kernel(const int* __restrict__ src, const int* __restrict__ dst,
                               const int* __restrict__ etype, const int* __restrict__ offs6,
                               int* __restrict__ cur, int* __restrict__ csrc, int E) {
  int e = blockIdx.x * blockDim.x + threadIdx.x;
  if (e < E) {
    int key = dst[e] * NREL + etype[e];
    int p = offs6[key] + atomicAdd(&cur[key], 1);
    csrc[p] = src[e] << 8;   // byte offset into 256-B rows
  }
}

// ---------------------------------------------------------------------------
// RGCN aggregation, one WAVE per node, rel-sorted edges, PREFIX SNAPSHOT.
// 16-deep unrolled gather loop (16 loads in flight; gather-latency-bound).
// ---------------------------------------------------------------------------
__launch_bounds__(256)
__global__ void rgcn_agg(const unsigned short* __restrict__ xh, const int* __restrict__ offs6,
                         const int* __restrict__ csrc,
                         unsigned short* __restrict__ aggh, int N) {
  int node = blockIdx.x * 4 + (threadIdx.x >> 6);
  if (node >= N) return;
  int lane = threadIdx.x & 63;
  const char* xc = (const char*)xh;
  const int* bp = offs6 + node * NREL;
  const int b0 = bp[0];
  int bn0 = bp[1], bn1 = bp[2], bn2 = bp[3], bn3 = bp[4], bn4 = bp[5], bn5 = bp[6];
  const int b6 = bn5;
  unsigned* ap = (unsigned*)(aggh + (long long)node * (NREL * FDIM)) + lane;

  float tx = 0.f, ty = 0.f;
  float px = 0.f, py = 0.f;
  int bprev = b0, snaps = 0;

#define FLUSH(EPOS)                                                          \
  while (snaps < NREL && bn0 == (EPOS)) {                                    \
    int cnt_ = (EPOS) - bprev;                                               \
    float inv_ = cnt_ ? 1.f / (float)cnt_ : 0.f;                             \
    union { _Float16 h[2]; unsigned u; } pk_;                                \
    pk_.h[0] = (_Float16)((tx - px) * inv_);                                 \
    pk_.h[1] = (_Float16)((ty - py) * inv_);                                 \
    *ap = pk_.u; ap += 64;                                                   \
    px = tx; py = ty; bprev = (EPOS); ++snaps;                               \
    bn0 = bn1; bn1 = bn2; bn2 = bn3; bn3 = bn4; bn4 = bn5;                   \
  }

#define EAT(XU)                                                              \
  {                                                                          \
    union { unsigned u; _Float16 h[2]; } c_; c_.u = (XU);                    \
    tx += (float)c_.h[0]; ty += (float)c_.h[1];                              \
  }

  FLUSH(b0)
  int e = b0;
  for (; e + 16 <= b6; e += 16) {
    unsigned xv[16];
#pragma unroll
    for (int t = 0; t < 16; ++t)
      xv[t] = ((const unsigned*)(xc + csrc[e + t]))[lane];
    EAT(xv[0])  FLUSH(e + 1)   EAT(xv[1])  FLUSH(e + 2)
    EAT(xv[2])  FLUSH(e + 3)   EAT(xv[3])  FLUSH(e + 4)
    EAT(xv[4])  FLUSH(e + 5)   EAT(xv[5])  FLUSH(e + 6)
    EAT(xv[6])  FLUSH(e + 7)   EAT(xv[7])  FLUSH(e + 8)
    EAT(xv[8])  FLUSH(e + 9)   EAT(xv[9])  FLUSH(e + 10)
    EAT(xv[10]) FLUSH(e + 11)  EAT(xv[11]) FLUSH(e + 12)
    EAT(xv[12]) FLUSH(e + 13)  EAT(xv[13]) FLUSH(e + 14)
    EAT(xv[14]) FLUSH(e + 15)  EAT(xv[15]) FLUSH(e + 16)
  }
  for (; e + 4 <= b6; e += 4) {
    unsigned y0 = ((const unsigned*)(xc + csrc[e + 0]))[lane];
    unsigned y1 = ((const unsigned*)(xc + csrc[e + 1]))[lane];
    unsigned y2 = ((const unsigned*)(xc + csrc[e + 2]))[lane];
    unsigned y3 = ((const unsigned*)(xc + csrc[e + 3]))[lane];
    EAT(y0) FLUSH(e + 1) EAT(y1) FLUSH(e + 2)
    EAT(y2) FLUSH(e + 3) EAT(y3) FLUSH(e + 4)
  }
  for (; e < b6; ++e) {
    unsigned xv = ((const unsigned*)(xc + csrc[e]))[lane];
    EAT(xv) FLUSH(e + 1)
  }
#undef EAT
#undef FLUSH
}

// ---------------------------------------------------------------------------
// TransformerConv edge-softmax + fused BN-stats accumulation.
// One WAVE per node, QUAD-edge processing (R11-proven).
// ---------------------------------------------------------------------------
__launch_bounds__(256)
__global__ void attn_kernel(const unsigned short* __restrict__ qh,
                            const unsigned short* __restrict__ kh,
                            const unsigned short* __restrict__ vh,
                            const int* __restrict__ offs6, const int* __restrict__ csrc,
                            float* __restrict__ out,
                            float* __restrict__ gsumB, float* __restrict__ gsqB, int N) {
  __shared__ float bsum[4][FDIM];
  __shared__ float bsq[4][FDIM];
  int wv = threadIdx.x >> 6;
  int node = blockIdx.x * 4 + wv;
  int lane = threadIdx.x & 63;
  bool active = (node < N);
  int start = 0, end = 0;
  if (active) { start = offs6[node * NREL]; end = offs6[node * NREL + NREL]; }
  int deg = end - start;

  const int g16 = lane >> 4;
  const int f = lane & 15;
  const char* kc = (const char*)kh;
  const char* vc = (const char*)vh;

  union U4 { uint4 u; h16x2 h[4]; };
  U4 qf;
  if (active) qf.u = *(const uint4*)(qh + (long long)node * FDIM + f * 8);

  float m = -INFINITY, den = 0.f, acc0 = 0.f, acc1 = 0.f;

#define LOADQ(E0, S0, S1, S2, S3, KU, V0, V1, V2, V3)                        \
  {                                                                          \
    S0 = csrc[(E0) + (g16 ^ 0)];                                             \
    S1 = csrc[(E0) + (g16 ^ 1)];                                             \
    S2 = csrc[(E0) + (g16 ^ 2)];                                             \
    S3 = csrc[(E0) + (g16 ^ 3)];                                             \
    KU = *(const uint4*)(kc + S0 + f * 16);                                  \
    V0 = ((const unsigned*)(vc + S0))[lane];                                 \
    V1 = ((const unsigned*)(vc + S1))[lane];                                 \
    V2 = ((const unsigned*)(vc + S2))[lane];                                 \
    V3 = ((const unsigned*)(vc + S3))[lane];                                 \
  }

#define PROCESS(KU, V0, V1, V2, V3, MASKED, M0, M1, M2, M3)                  \
  {                                                                          \
    U4 kf; kf.u = KU;                                                        \
    float pd = FDOT2(qf.h[0], kf.h[0], 0.f);                                 \
    pd = FDOT2(qf.h[1], kf.h[1], pd);                                        \
    pd = FDOT2(qf.h[2], kf.h[2], pd);                                        \
    pd = FDOT2(qf.h[3], kf.h[3], pd);                                        \
    pd += __shfl_xor(pd, 1);  pd += __shfl_xor(pd, 2);                       \
    pd += __shfl_xor(pd, 4);  pd += __shfl_xor(pd, 8);                       \
    float sc0 = pd;                                                          \
    float sc1 = __shfl_xor(pd, 16);                                          \
    float sc2 = __shfl_xor(pd, 32);                                          \
    float sc3 = __shfl_xor(pd, 48);                                          \
    if (MASKED) {                                                            \
      if (!(M0)) sc0 = -INFINITY;                                            \
      if (!(M1)) sc1 = -INFINITY;                                            \
      if (!(M2)) sc2 = -INFINITY;                                            \
      if (!(M3)) sc3 = -INFINITY;                                            \
    }                                                                        \
    float mx = fmaxf(fmaxf(sc0, sc1), fmaxf(sc2, sc3));                      \
    float mn = fmaxf(m, mx);                                                 \
    float scl = exp2f(m - mn);                                               \
    float a0 = exp2f(sc0 - mn), a1 = exp2f(sc1 - mn);                        \
    float a2 = exp2f(sc2 - mn), a3 = exp2f(sc3 - mn);                        \
    den = den * scl + ((a0 + a1) + (a2 + a3));                               \
    union { unsigned u; _Float16 h[2]; } w0, w1, w2, w3;                     \
    w0.u = V0; w1.u = V1; w2.u = V2; w3.u = V3;                              \
    acc0 = acc0 * scl + a0 * (float)w0.h[0] + a1 * (float)w1.h[0]            \
                      + a2 * (float)w2.h[0] + a3 * (float)w3.h[0];           \
    acc1 = acc1 * scl + a0 * (float)w0.h[1] + a1 * (float)w1.h[1]            \
                      + a2 * (float)w2.h[1] + a3 * (float)w3.h[1];           \
    m = mn;                                                                  \
  }

  if (deg > 0) {
    int nfull4 = deg & ~3;
    int e = start;
    if (nfull4 > 0) {
      int sA0, sA1, sA2, sA3; uint4 kA; unsigned vA0, vA1, vA2, vA3;
      LOADQ(e, sA0, sA1, sA2, sA3, kA, vA0, vA1, vA2, vA3)
      for (; e < start + nfull4; e += 4) {
        int sB0, sB1, sB2, sB3; uint4 kB; unsigned vB0, vB1, vB2, vB3;
        bool more = (e + 4 < start + nfull4);
        if (more) LOADQ(e + 4, sB0, sB1, sB2, sB3, kB, vB0, vB1, vB2, vB3)
        PROCESS(kA, vA0, vA1, vA2, vA3, false, 1, 1, 1, 1)
        if (more) { kA = kB; vA0 = vB0; vA1 = vB1; vA2 = vB2; vA3 = vB3; }
      }
    }
    int rem = deg & 3;
    if (rem) {
      int e0 = start + nfull4;
      int j0 = g16 ^ 0, j1 = g16 ^ 1, j2 = g16 ^ 2, j3 = g16 ^ 3;
      int sT0 = csrc[e0 + (j0 < rem ? j0 : 0)];
      int sT1 = csrc[e0 + (j1 < rem ? j1 : 0)];
      int sT2 = csrc[e0 + (j2 < rem ? j2 : 0)];
      int sT3 = csrc[e0 + (j3 < rem ? j3 : 0)];
      uint4 kT = *(const uint4*)(kc + sT0 + f * 16);
      unsigned vT0 = ((const unsigned*)(vc + sT0))[lane];
      unsigned vT1 = ((const unsigned*)(vc + sT1))[lane];
      unsigned vT2 = ((const unsigned*)(vc + sT2))[lane];
      unsigned vT3 = ((const unsigned*)(vc + sT3))[lane];
      PROCESS(kT, vT0, vT1, vT2, vT3, true, j0 < rem, j1 < rem, j2 < rem, j3 < rem)
    }
  }
#undef LOADQ
#undef PROCESS

  float2 o = make_float2(0.f, 0.f);
  if (active) {
    float2* op = (float2*)(out + (long long)node * FDIM);
    o = op[lane];
    if (deg > 0) {
      float inv = 1.f / den;
      o.x += acc0 * inv;
      o.y += acc1 * inv;
      op[lane] = o;
    }
  }

  // ---- fused BN-stats: o is the final pre-BN value of this node ----
  ((float2*)bsum[wv])[lane] = make_float2(o.x, o.y);
  ((float2*)bsq[wv])[lane]  = make_float2(o.x * o.x, o.y * o.y);
  __syncthreads();
  if (threadIdx.x < FDIM) {
    int d = threadIdx.x;
    float s  = bsum[0][d] + bsum[1][d] + bsum[2][d] + bsum[3][d];
    float q2 = bsq[0][d]  + bsq[1][d]  + bsq[2][d]  + bsq[3][d];
    int bucket = blockIdx.x & 31;
    atomicAdd(&gsumB[bucket * FDIM + d], s);
    atomicAdd(&gsqB[bucket * FDIM + d], q2);
  }
}

// ---------------------------------------------------------------------------
// BatchNorm finalize (reduce 32 buckets) + LeakyReLU apply
// ---------------------------------------------------------------------------
__global__ void bn_final(const float* __restrict__ gsumB, const float* __restrict__ gsqB,
                         const float* __restrict__ gamma, const float* __restrict__ beta,
                         float* __restrict__ ss, int N) {
  int d = threadIdx.x;
  if (d < FDIM) {
    float s = 0.f, q = 0.f;
    for (int b = 0; b < 32; ++b) { s += gsumB[b * FDIM + d]; q += gsqB[b * FDIM + d]; }
    float mean = s / (float)N;
    float var = q / (float)N - mean * mean;
    var = fmaxf(var, 0.f);
    float sc = gamma[d] * rsqrtf(var + 1e-5f);
    ss[d] = sc;
    ss[FDIM + d] = beta[d] - mean * sc;
  }
}

__global__ void bn_apply(float* __restrict__ x, const float* __restrict__ ss, long long total4) {
  long long i = (long long)blockIdx.x * blockDim.x + threadIdx.x;
  if (i < total4) {
    int d0 = (int)((i * 4) & (FDIM - 1));
    float4 vv = ((const float4*)x)[i];
    float y0 = ss[d0 + 0] * vv.x + ss[FDIM + d0 + 0];
    float y1 = ss[d0 + 1] * vv.y + ss[FDIM + d0 + 1];
    float y2 = ss[d0 + 2] * vv.z + ss[FDIM + d0 + 2];
    float y3 = ss[d0 + 3] * vv.w + ss[FDIM + d0 + 3];
    vv.x = (y0 > 0.f) ? y0 : 0.01f * y0;
    vv.y = (y1 > 0.f) ? y1 : 0.01f * y1;
    vv.z = (y2 > 0.f) ? y2 : 0.01f * y2;
    vv.w = (y3 > 0.f) ? y3 : 0.01f * y3;
    ((float4*)x)[i] = vv;
  }
}

// ---------------------------------------------------------------------------
// Launcher
// ---------------------------------------------------------------------------
extern "C" void kernel_launch(void* const* d_in, const int* in_sizes, int n_in,
                              void* d_out, int out_size, void* d_ws, size_t ws_size,
                              hipStream_t stream) {
  const float* x         = (const float*)d_in[0];
  const int*   ei        = (const int*)d_in[1];
  const int*   etype     = (const int*)d_in[2];
  const float* rgcn_w    = (const float*)d_in[3];
  const float* rgcn_root = (const float*)d_in[4];
  const float* rgcn_bias = (const float*)d_in[5];
  const float* wq = (const float*)d_in[6];  const float* bq = (const float*)d_in[7];
  const float* wk = (const float*)d_in[8];  const float* bk = (const float*)d_in[9];
  const float* wv = (const float*)d_in[10]; const float* bv = (const float*)d_in[11];
  const float* wsk = (const float*)d_in[12]; const float* bsk = (const float*)d_in[13];
  const float* gamma = (const float*)d_in[14]; const float* beta = (const float*)d_in[15];

  const int N = in_sizes[0] / FDIM;
  const int E = in_sizes[1] / 2;
  const int* src = ei;
  const int* dst = ei + E;
  const int NK = N * NREL;

  // ---- workspace layout ----
  char* base = (char*)d_ws;
  size_t off = 0;
  auto alloc = [&](size_t bytes) -> char* {
    char* p = base + off;
    off += (bytes + 255) & ~(size_t)255;
    return p;
  };
  unsigned short* aggh = (unsigned short*)alloc((size_t)N * (NREL * FDIM) * 2);  // 76.8MB
  // q/k/v (all fp16) reuse the agg region after the fused GEMM consumes it:
  unsigned short* qbuf = aggh;
  unsigned short* kbuf = aggh + (size_t)N * FDIM;
  unsigned short* vbuf = aggh + 2 * (size_t)N * FDIM;
  unsigned short* xh   = (unsigned short*)alloc((size_t)N * FDIM * 2);
  unsigned short* btR  = (unsigned short*)alloc((size_t)896 * 128 * 2);
  unsigned short* btQ  = (unsigned short*)alloc((size_t)4 * 128 * 128 * 2);
  int* cnt6 = (int*)alloc((size_t)2 * NK * 4);
  int* cur  = cnt6 + NK;
  int* offs6 = (int*)alloc((size_t)(NK + 1) * 4);
  int* incl = (int*)alloc((size_t)NK * 4);
  int* part = (int*)alloc((size_t)512 * 4);
  int* csrc = (int*)alloc((size_t)E * 4);
  float* gsumB = (float*)alloc((size_t)32 * FDIM * 4);
  float* gsqB  = (float*)alloc((size_t)32 * FDIM * 4);
  float* ss    = (float*)alloc((size_t)2 * FDIM * 4);

  float* out = (float*)d_out;

  hipMemsetAsync(cnt6, 0, (size_t)2 * NK * sizeof(int), stream);
  hipMemsetAsync(gsumB, 0, (size_t)64 * FDIM * sizeof(float), stream);  // gsumB+gsqB

  // ---- conversions ----
  int n4 = N * FDIM / 4;
  cvt_x_kernel<<<(n4 + 255) / 256, 256, 0, stream>>>(x, xh, n4);
  cvt_wr_kernel<<<(896 * 128 + 255) / 256, 256, 0, stream>>>(rgcn_root, rgcn_w, btR);
  WPtrs wp; wp.W[0] = wq; wp.W[1] = wk; wp.W[2] = wv; wp.W[3] = wsk;
  cvt_wq_kernel<<<(4 * 128 * 128 + 255) / 256, 256, 0, stream>>>(wp, btQ);

  // ---- CSR build over (dst, rel) keys ----
  hist_kernel<<<(E + 255) / 256, 256, 0, stream>>>(dst, etype, cnt6, E);
  int nb = (NK + 1023) / 1024;
  scan1<<<nb, 1024, 0, stream>>>(cnt6, incl, part, NK);
  scan2<<<1, 64, 0, stream>>>(part, nb);
  scan3<<<(NK + 255) / 256, 256, 0, stream>>>(incl, part, offs6, NK);
  scatter_kernel<<<(E + 255) / 256, 256, 0, stream>>>(src, dst, etype, offs6, cur, csrc, E);

  const int nodeBlocks = (N + 3) / 4;
  const int gemmBlocks = (N + 63) / 64;

  // ---- RGCN aggregate-first, then FUSED GEMM (h + q/k/v/skip in one pass) ----
  rgcn_agg<<<nodeBlocks, 256, 0, stream>>>(xh, offs6, csrc, aggh, N);

  GArgs g = {};
  g.Ax = xh; g.Aagg = aggh; g.BtR = btR; g.BtQ = btQ;
  g.biasR = rgcn_bias;
  g.bias2[0] = bq; g.bias2[1] = bk; g.bias2[2] = bv; g.bias2[3] = bsk;
  g.qh = qbuf; g.kh = kbuf; g.vh = vbuf; g.sk = out;
  g.M = N;
  gemm_fused<<<gemmBlocks, 256, 0, stream>>>(g);

  // ---- edge-softmax attention + fused BN-stats ----
  attn_kernel<<<nodeBlocks, 256, 0, stream>>>(qbuf, kbuf, vbuf, offs6, csrc, out,
                                              gsumB, gsqB, N);

  // ---- BatchNorm finalize + apply ----
  bn_final<<<1, 128, 0, stream>>>(gsumB, gsqB, gamma, beta, ss, N);
  long long total4 = (long long)N * FDIM / 4;
  bn_apply<<<(int)((total4 + 255) / 256), 256, 0, stream>>>(out, ss, total4);
}

// Round 17
// 305.244 us; speedup vs baseline: 1.2105x; 1.0741x over previous
//
#include <hip/hip_runtime.h>
#include <hip/hip_bf16.h>
#include <math.h>

#define FDIM 128
#define NREL 6

typedef _Float16 half8 __attribute__((ext_vector_type(8)));
typedef _Float16 h16x2 __attribute__((ext_vector_type(2)));
typedef float f32x4 __attribute__((ext_vector_type(4)));

#if __has_builtin(__builtin_amdgcn_fdot2)
#define FDOT2(A, B, C) __builtin_amdgcn_fdot2((A), (B), (C), false)
#else
#define FDOT2(A, B, C) ((float)(A)[0] * (float)(B)[0] + ((float)(A)[1] * (float)(B)[1] + (C)))
#endif

// ---------------- fp16 helpers ----------------------------------------------
static __device__ __forceinline__ unsigned short f2h(float f) {
  union { _Float16 h; unsigned short u; } p; p.h = (_Float16)f; return p.u;
}

// ---------------------------------------------------------------------------
// dtype conversion passes
// ---------------------------------------------------------------------------
__global__ void cvt_x_kernel(const float* __restrict__ x, unsigned short* __restrict__ xh,
                             int n4) {
  int i = blockIdx.x * 256 + threadIdx.x;
  if (i < n4) {
    float4 v = ((const float4*)x)[i];
    union { _Float16 h[4]; uint2 u; } p;
    p.h[0] = (_Float16)v.x; p.h[1] = (_Float16)v.y;
    p.h[2] = (_Float16)v.z; p.h[3] = (_Float16)v.w;
    ((uint2*)xh)[i] = p.u;
  }
}

// Bt_rgcn[n][kk] (n<128, kk<896) = (kk<128 ? root[kk][n] : w[kk-128][n]) as fp16
__global__ void cvt_wr_kernel(const float* __restrict__ root, const float* __restrict__ w,
                              unsigned short* __restrict__ bt) {
  int i = blockIdx.x * 256 + threadIdx.x;
  if (i < 896 * 128) {
    int n = i / 896, kk = i - n * 896;
    float v = (kk < 128) ? root[kk * 128 + n] : w[(long long)(kk - 128) * 128 + n];
    bt[i] = f2h(v);
  }
}

// Bt_qkvs[z][n][kk] = W_z[kk][n] as fp16
struct WPtrs { const float* W[4]; };
__global__ void cvt_wq_kernel(WPtrs wp, unsigned short* __restrict__ bt) {
  int i = blockIdx.x * 256 + threadIdx.x;
  if (i < 4 * 128 * 128) {
    int z = i >> 14;
    int r = i & 16383;
    int n = r >> 7, kk = r & 127;
    bt[i] = f2h(wp.W[z][kk * 128 + n]);
  }
}

// ---------------------------------------------------------------------------
// fp16 MFMA GEMM, tile 64(M) x 128(N), BK=64, 256 thr = 4 waves (2M x 2N).
// R11-proven SPLIT structure (the fused variants R13-R16 were all latency-
// bound at 96-134us; split keeps ~4 blocks/CU and both GEMMs under ~35us).
// XOR-swizzled LDS (T2); B pre-transposed [z][128(n)][K] fp16.
// ---------------------------------------------------------------------------
struct GArgs {
  const unsigned short* Ax;    // fp16 [M][128]  (x_h or h_h)
  const unsigned short* Aagg;  // fp16 [M][768]  (MODE0)
  const unsigned short* Bt;    // fp16 [z][128(n)][K]
  const float* bias[4];
  unsigned short* qh; unsigned short* kh; unsigned short* vh; float* sk;  // MODE1
  unsigned short* h;                                                      // MODE0
  int M, K;
};

template <int MODE>
__launch_bounds__(256)
__global__ void gemm_mfma(GArgs g) {
  __shared__ unsigned short Ah[64 * 64];    // [r][8 x 16B units], swizzled
  __shared__ unsigned short Bh[128 * 64];   // [n][8 x 16B units], swizzled
  const int tid = threadIdx.x;
  const int lane = tid & 63;
  const int wid = tid >> 6;
  const int wm = wid >> 1, wn = wid & 1;
  const int lr = lane & 15, lk = lane >> 4;
  const int m0 = blockIdx.x * 64;
  const int z = (MODE == 1) ? blockIdx.z : 0;
  const unsigned short* Bt = g.Bt + (long long)z * 128 * g.K;
  const int K = g.K;
  const int M = g.M;

  f32x4 acc[2][4];
#pragma unroll
  for (int a = 0; a < 2; ++a)
#pragma unroll
    for (int b = 0; b < 4; ++b) { acc[a][b][0] = 0.f; acc[a][b][1] = 0.f; acc[a][b][2] = 0.f; acc[a][b][3] = 0.f; }

  for (int k0 = 0; k0 < K; k0 += 64) {
    __syncthreads();
    // ---- stage A: 64 rows x 8 col16 units ----
#pragma unroll
    for (int p = 0; p < 2; ++p) {
      int idx = tid + 256 * p;
      int r = idx >> 3, c = idx & 7;
      int row = m0 + r; if (row > M - 1) row = M - 1;   // clamp tail (store guarded)
      const unsigned short* srcp;
      if (MODE == 0)
        srcp = (k0 < 128) ? (g.Ax + (long long)row * 128 + k0 + c * 8)
                          : (g.Aagg + (long long)row * 768 + (k0 - 128) + c * 8);
      else
        srcp = g.Ax + (long long)row * 128 + k0 + c * 8;
      uint4 u = *(const uint4*)srcp;
      ((uint4*)Ah)[r * 8 + (c ^ (r & 7))] = u;
    }
    // ---- stage B: 128 n-rows x 8 col16 units ----
#pragma unroll
    for (int p = 0; p < 4; ++p) {
      int idx = tid + 256 * p;
      int rn = idx >> 3, c = idx & 7;
      uint4 u = *(const uint4*)(Bt + (long long)rn * K + k0 + c * 8);
      ((uint4*)Bh)[rn * 8 + (c ^ (rn & 7))] = u;
    }
    __syncthreads();
    // ---- fragments + MFMA (2 K32 sub-steps) ----
#pragma unroll
    for (int ks = 0; ks < 2; ++ks) {
      half8 a[2], b[4];
#pragma unroll
      for (int fm = 0; fm < 2; ++fm) {
        int row = wm * 32 + fm * 16 + lr;
        a[fm] = *(const half8*)&((uint4*)Ah)[row * 8 + ((ks * 4 + lk) ^ (row & 7))];
      }
#pragma unroll
      for (int fn = 0; fn < 4; ++fn) {
        int col = wn * 64 + fn * 16 + lr;
        b[fn] = *(const half8*)&((uint4*)Bh)[col * 8 + ((ks * 4 + lk) ^ (col & 7))];
      }
#pragma unroll
      for (int fm = 0; fm < 2; ++fm)
#pragma unroll
        for (int fn = 0; fn < 4; ++fn)
          acc[fm][fn] = __builtin_amdgcn_mfma_f32_16x16x32_f16(a[fm], b[fn], acc[fm][fn], 0, 0, 0);
    }
  }

  // ---- epilogue ----
  const float CF = 0.08838834764831845f * 1.4426950408889634f;  // 1/sqrt(128)*log2(e)
  const float* bias = (MODE == 0) ? g.bias[0] : g.bias[z];
#pragma unroll
  for (int fm = 0; fm < 2; ++fm) {
#pragma unroll
    for (int fn = 0; fn < 4; ++fn) {
      int col = wn * 64 + fn * 16 + lr;
      float bv = bias[col];
#pragma unroll
      for (int j = 0; j < 4; ++j) {
        int row = m0 + wm * 32 + fm * 16 + lk * 4 + j;
        if (row < M) {
          float vv = acc[fm][fn][j] + bv;
          long long off = (long long)row * 128 + col;
          if (MODE == 0) {
            g.h[off] = f2h(vv);
          } else {
            if (z == 0) g.qh[off] = f2h(vv * CF);       // scale folded into q
            else if (z == 1) g.kh[off] = f2h(vv);
            else if (z == 2) g.vh[off] = f2h(vv);
            else g.sk[off] = vv;
          }
        }
      }
    }
  }
}

// ---------------------------------------------------------------------------
// CSR construction over (dst, rel) keys; csrc stores BYTE offsets (src*256).
// ---------------------------------------------------------------------------
__global__ void hist_kernel(const int* __restrict__ dst, const int* __restrict__ etype,
                            int* __restrict__ cnt, int E) {
  int e = blockIdx.x * blockDim.x + threadIdx.x;
  if (e < E) atomicAdd(&cnt[dst[e] * NREL + etype[e]], 1);
}

__launch_bounds__(1024)
__global__ void scan1(const int* __restrict__ deg, int* __restrict__ incl,
                      int* __restrict__ part, int n) {
  __shared__ int sh[1024];
  int tid = threadIdx.x;
  int i = blockIdx.x * 1024 + tid;
  sh[tid] = (i < n) ? deg[i] : 0;
  __syncthreads();
  for (int o = 1; o < 1024; o <<= 1) {
    int t = (tid >= o) ? sh[tid - o] : 0;
    __syncthreads();
    sh[tid] += t;
    __syncthreads();
  }
  if (i < n) incl[i] = sh[tid];
  if (tid == 1023) part[blockIdx.x] = sh[1023];
}

__global__ void scan2(int* part, int nb) {
  int lane = threadIdx.x;  // 64 threads
  int run = 0;
  for (int b0 = 0; b0 < nb; b0 += 64) {
    int i = b0 + lane;
    int orig = (i < nb) ? part[i] : 0;
    int v = orig;
#pragma unroll
    for (int o = 1; o < 64; o <<= 1) {
      int t = __shfl_up(v, o);
      if (lane >= o) v += t;
    }
    if (i < nb) part[i] = run + v - orig;  // exclusive
    run += __shfl(v, 63);
  }
}

__global__ void scan3(const int* __restrict__ incl, const int* __restrict__ part,
                      int* __restrict__ offs, int n) {
  int i = blockIdx.x * blockDim.x + threadIdx.x;
  if (i < n) {
    offs[i + 1] = incl[i] + part[i >> 10];
    if (i == 0) offs[0] = 0;
  }
}

__global__ void scatter_kernel(const int* __restrict__ src, const int* __restrict__ dst,
                               const int* __restrict__ etype, const int* __restrict__ offs6,
                               int* __restrict__ cur, int* __restrict__ csrc, int E) {
  int e = blockIdx.x * blockDim.x + threadIdx.x;
  if (e < E) {
    int key = dst[e] * NREL + etype[e];
    int p = offs6[key] + atomicAdd(&cur[key], 1);
    csrc[p] = src[e] << 8;   // byte offset into 256-B rows
  }
}

// ---------------------------------------------------------------------------
// RGCN aggregation, one WAVE per node, rel-sorted edges, PREFIX SNAPSHOT.
// 16-deep unrolled gather loop (16 loads in flight; gather-latency-bound).
// ---------------------------------------------------------------------------
__launch_bounds__(256)
__global__ void rgcn_agg(const unsigned short* __restrict__ xh, const int* __restrict__ offs6,
                         const int* __restrict__ csrc,
                         unsigned short* __restrict__ aggh, int N) {
  int node = blockIdx.x * 4 + (threadIdx.x >> 6);
  if (node >= N) return;
  int lane = threadIdx.x & 63;
  const char* xc = (const char*)xh;
  const int* bp = offs6 + node * NREL;
  const int b0 = bp[0];
  int bn0 = bp[1], bn1 = bp[2], bn2 = bp[3], bn3 = bp[4], bn4 = bp[5], bn5 = bp[6];
  const int b6 = bn5;
  unsigned* ap = (unsigned*)(aggh + (long long)node * (NREL * FDIM)) + lane;

  float tx = 0.f, ty = 0.f;
  float px = 0.f, py = 0.f;
  int bprev = b0, snaps = 0;

#define FLUSH(EPOS)                                                          \
  while (snaps < NREL && bn0 == (EPOS)) {                                    \
    int cnt_ = (EPOS) - bprev;                                               \
    float inv_ = cnt_ ? 1.f / (float)cnt_ : 0.f;                             \
    union { _Float16 h[2]; unsigned u; } pk_;                                \
    pk_.h[0] = (_Float16)((tx - px) * inv_);                                 \
    pk_.h[1] = (_Float16)((ty - py) * inv_);                                 \
    *ap = pk_.u; ap += 64;                                                   \
    px = tx; py = ty; bprev = (EPOS); ++snaps;                               \
    bn0 = bn1; bn1 = bn2; bn2 = bn3; bn3 = bn4; bn4 = bn5;                   \
  }

#define EAT(XU)                                                              \
  {                                                                          \
    union { unsigned u; _Float16 h[2]; } c_; c_.u = (XU);                    \
    tx += (float)c_.h[0]; ty += (float)c_.h[1];                              \
  }

  FLUSH(b0)
  int e = b0;
  for (; e + 16 <= b6; e += 16) {
    unsigned xv[16];
#pragma unroll
    for (int t = 0; t < 16; ++t)
      xv[t] = ((const unsigned*)(xc + csrc[e + t]))[lane];
    EAT(xv[0])  FLUSH(e + 1)   EAT(xv[1])  FLUSH(e + 2)
    EAT(xv[2])  FLUSH(e + 3)   EAT(xv[3])  FLUSH(e + 4)
    EAT(xv[4])  FLUSH(e + 5)   EAT(xv[5])  FLUSH(e + 6)
    EAT(xv[6])  FLUSH(e + 7)   EAT(xv[7])  FLUSH(e + 8)
    EAT(xv[8])  FLUSH(e + 9)   EAT(xv[9])  FLUSH(e + 10)
    EAT(xv[10]) FLUSH(e + 11)  EAT(xv[11]) FLUSH(e + 12)
    EAT(xv[12]) FLUSH(e + 13)  EAT(xv[13]) FLUSH(e + 14)
    EAT(xv[14]) FLUSH(e + 15)  EAT(xv[15]) FLUSH(e + 16)
  }
  for (; e + 4 <= b6; e += 4) {
    unsigned y0 = ((const unsigned*)(xc + csrc[e + 0]))[lane];
    unsigned y1 = ((const unsigned*)(xc + csrc[e + 1]))[lane];
    unsigned y2 = ((const unsigned*)(xc + csrc[e + 2]))[lane];
    unsigned y3 = ((const unsigned*)(xc + csrc[e + 3]))[lane];
    EAT(y0) FLUSH(e + 1) EAT(y1) FLUSH(e + 2)
    EAT(y2) FLUSH(e + 3) EAT(y3) FLUSH(e + 4)
  }
  for (; e < b6; ++e) {
    unsigned xv = ((const unsigned*)(xc + csrc[e]))[lane];
    EAT(xv) FLUSH(e + 1)
  }
#undef EAT
#undef FLUSH
}

// ---------------------------------------------------------------------------
// TransformerConv edge-softmax + fused BN-stats accumulation.
// One WAVE per node, QUAD-edge processing (R11-proven).
// ---------------------------------------------------------------------------
__launch_bounds__(256)
__global__ void attn_kernel(const unsigned short* __restrict__ qh,
                            const unsigned short* __restrict__ kh,
                            const unsigned short* __restrict__ vh,
                            const int* __restrict__ offs6, const int* __restrict__ csrc,
                            float* __restrict__ out,
                            float* __restrict__ gsumB, float* __restrict__ gsqB, int N) {
  __shared__ float bsum[4][FDIM];
  __shared__ float bsq[4][FDIM];
  int wv = threadIdx.x >> 6;
  int node = blockIdx.x * 4 + wv;
  int lane = threadIdx.x & 63;
  bool active = (node < N);
  int start = 0, end = 0;
  if (active) { start = offs6[node * NREL]; end = offs6[node * NREL + NREL]; }
  int deg = end - start;

  const int g16 = lane >> 4;
  const int f = lane & 15;
  const char* kc = (const char*)kh;
  const char* vc = (const char*)vh;

  union U4 { uint4 u; h16x2 h[4]; };
  U4 qf;
  if (active) qf.u = *(const uint4*)(qh + (long long)node * FDIM + f * 8);

  float m = -INFINITY, den = 0.f, acc0 = 0.f, acc1 = 0.f;

#define LOADQ(E0, S0, S1, S2, S3, KU, V0, V1, V2, V3)                        \
  {                                                                          \
    S0 = csrc[(E0) + (g16 ^ 0)];                                             \
    S1 = csrc[(E0) + (g16 ^ 1)];                                             \
    S2 = csrc[(E0) + (g16 ^ 2)];                                             \
    S3 = csrc[(E0) + (g16 ^ 3)];                                             \
    KU = *(const uint4*)(kc + S0 + f * 16);                                  \
    V0 = ((const unsigned*)(vc + S0))[lane];                                 \
    V1 = ((const unsigned*)(vc + S1))[lane];                                 \
    V2 = ((const unsigned*)(vc + S2))[lane];                                 \
    V3 = ((const unsigned*)(vc + S3))[lane];                                 \
  }

#define PROCESS(KU, V0, V1, V2, V3, MASKED, M0, M1, M2, M3)                  \
  {                                                                          \
    U4 kf; kf.u = KU;                                                        \
    float pd = FDOT2(qf.h[0], kf.h[0], 0.f);                                 \
    pd = FDOT2(qf.h[1], kf.h[1], pd);                                        \
    pd = FDOT2(qf.h[2], kf.h[2], pd);                                        \
    pd = FDOT2(qf.h[3], kf.h[3], pd);                                        \
    pd += __shfl_xor(pd, 1);  pd += __shfl_xor(pd, 2);                       \
    pd += __shfl_xor(pd, 4);  pd += __shfl_xor(pd, 8);                       \
    float sc0 = pd;                                                          \
    float sc1 = __shfl_xor(pd, 16);                                          \
    float sc2 = __shfl_xor(pd, 32);                                          \
    float sc3 = __shfl_xor(pd, 48);                                          \
    if (MASKED) {                                                            \
      if (!(M0)) sc0 = -INFINITY;                                            \
      if (!(M1)) sc1 = -INFINITY;                                            \
      if (!(M2)) sc2 = -INFINITY;                                            \
      if (!(M3)) sc3 = -INFINITY;                                            \
    }                                                                        \
    float mx = fmaxf(fmaxf(sc0, sc1), fmaxf(sc2, sc3));                      \
    float mn = fmaxf(m, mx);                                                 \
    float scl = exp2f(m - mn);                                               \
    float a0 = exp2f(sc0 - mn), a1 = exp2f(sc1 - mn);                        \
    float a2 = exp2f(sc2 - mn), a3 = exp2f(sc3 - mn);                        \
    den = den * scl + ((a0 + a1) + (a2 + a3));                               \
    union { unsigned u; _Float16 h[2]; } w0, w1, w2, w3;                     \
    w0.u = V0; w1.u = V1; w2.u = V2; w3.u = V3;                              \
    acc0 = acc0 * scl + a0 * (float)w0.h[0] + a1 * (float)w1.h[0]            \
                      + a2 * (float)w2.h[0] + a3 * (float)w3.h[0];           \
    acc1 = acc1 * scl + a0 * (float)w0.h[1] + a1 * (float)w1.h[1]            \
                      + a2 * (float)w2.h[1] + a3 * (float)w3.h[1];           \
    m = mn;                                                                  \
  }

  if (deg > 0) {
    int nfull4 = deg & ~3;
    int e = start;
    if (nfull4 > 0) {
      int sA0, sA1, sA2, sA3; uint4 kA; unsigned vA0, vA1, vA2, vA3;
      LOADQ(e, sA0, sA1, sA2, sA3, kA, vA0, vA1, vA2, vA3)
      for (; e < start + nfull4; e += 4) {
        int sB0, sB1, sB2, sB3; uint4 kB; unsigned vB0, vB1, vB2, vB3;
        bool more = (e + 4 < start + nfull4);
        if (more) LOADQ(e + 4, sB0, sB1, sB2, sB3, kB, vB0, vB1, vB2, vB3)
        PROCESS(kA, vA0, vA1, vA2, vA3, false, 1, 1, 1, 1)
        if (more) { kA = kB; vA0 = vB0; vA1 = vB1; vA2 = vB2; vA3 = vB3; }
      }
    }
    int rem = deg & 3;
    if (rem) {
      int e0 = start + nfull4;
      int j0 = g16 ^ 0, j1 = g16 ^ 1, j2 = g16 ^ 2, j3 = g16 ^ 3;
      int sT0 = csrc[e0 + (j0 < rem ? j0 : 0)];
      int sT1 = csrc[e0 + (j1 < rem ? j1 : 0)];
      int sT2 = csrc[e0 + (j2 < rem ? j2 : 0)];
      int sT3 = csrc[e0 + (j3 < rem ? j3 : 0)];
      uint4 kT = *(const uint4*)(kc + sT0 + f * 16);
      unsigned vT0 = ((const unsigned*)(vc + sT0))[lane];
      unsigned vT1 = ((const unsigned*)(vc + sT1))[lane];
      unsigned vT2 = ((const unsigned*)(vc + sT2))[lane];
      unsigned vT3 = ((const unsigned*)(vc + sT3))[lane];
      PROCESS(kT, vT0, vT1, vT2, vT3, true, j0 < rem, j1 < rem, j2 < rem, j3 < rem)
    }
  }
#undef LOADQ
#undef PROCESS

  float2 o = make_float2(0.f, 0.f);
  if (active) {
    float2* op = (float2*)(out + (long long)node * FDIM);
    o = op[lane];
    if (deg > 0) {
      float inv = 1.f / den;
      o.x += acc0 * inv;
      o.y += acc1 * inv;
      op[lane] = o;
    }
  }

  // ---- fused BN-stats: o is the final pre-BN value of this node ----
  ((float2*)bsum[wv])[lane] = make_float2(o.x, o.y);
  ((float2*)bsq[wv])[lane]  = make_float2(o.x * o.x, o.y * o.y);
  __syncthreads();
  if (threadIdx.x < FDIM) {
    int d = threadIdx.x;
    float s  = bsum[0][d] + bsum[1][d] + bsum[2][d] + bsum[3][d];
    float q2 = bsq[0][d]  + bsq[1][d]  + bsq[2][d]  + bsq[3][d];
    int bucket = blockIdx.x & 31;
    atomicAdd(&gsumB[bucket * FDIM + d], s);
    atomicAdd(&gsqB[bucket * FDIM + d], q2);
  }
}

// ---------------------------------------------------------------------------
// BatchNorm finalize (reduce 32 buckets) + LeakyReLU apply
// ---------------------------------------------------------------------------
__global__ void bn_final(const float* __restrict__ gsumB, const float* __restrict__ gsqB,
                         const float* __restrict__ gamma, const float* __restrict__ beta,
                         float* __restrict__ ss, int N) {
  int d = threadIdx.x;
  if (d < FDIM) {
    float s = 0.f, q = 0.f;
    for (int b = 0; b < 32; ++b) { s += gsumB[b * FDIM + d]; q += gsqB[b * FDIM + d]; }
    float mean = s / (float)N;
    float var = q / (float)N - mean * mean;
    var = fmaxf(var, 0.f);
    float sc = gamma[d] * rsqrtf(var + 1e-5f);
    ss[d] = sc;
    ss[FDIM + d] = beta[d] - mean * sc;
  }
}

__global__ void bn_apply(float* __restrict__ x, const float* __restrict__ ss, long long total4) {
  long long i = (long long)blockIdx.x * blockDim.x + threadIdx.x;
  if (i < total4) {
    int d0 = (int)((i * 4) & (FDIM - 1));
    float4 vv = ((const float4*)x)[i];
    float y0 = ss[d0 + 0] * vv.x + ss[FDIM + d0 + 0];
    float y1 = ss[d0 + 1] * vv.y + ss[FDIM + d0 + 1];
    float y2 = ss[d0 + 2] * vv.z + ss[FDIM + d0 + 2];
    float y3 = ss[d0 + 3] * vv.w + ss[FDIM + d0 + 3];
    vv.x = (y0 > 0.f) ? y0 : 0.01f * y0;
    vv.y = (y1 > 0.f) ? y1 : 0.01f * y1;
    vv.z = (y2 > 0.f) ? y2 : 0.01f * y2;
    vv.w = (y3 > 0.f) ? y3 : 0.01f * y3;
    ((float4*)x)[i] = vv;
  }
}

// ---------------------------------------------------------------------------
// Launcher
// ---------------------------------------------------------------------------
extern "C" void kernel_launch(void* const* d_in, const int* in_sizes, int n_in,
                              void* d_out, int out_size, void* d_ws, size_t ws_size,
                              hipStream_t stream) {
  const float* x         = (const float*)d_in[0];
  const int*   ei        = (const int*)d_in[1];
  const int*   etype     = (const int*)d_in[2];
  const float* rgcn_w    = (const float*)d_in[3];
  const float* rgcn_root = (const float*)d_in[4];
  const float* rgcn_bias = (const float*)d_in[5];
  const float* wq = (const float*)d_in[6];  const float* bq = (const float*)d_in[7];
  const float* wk = (const float*)d_in[8];  const float* bk = (const float*)d_in[9];
  const float* wv = (const float*)d_in[10]; const float* bv = (const float*)d_in[11];
  const float* wsk = (const float*)d_in[12]; const float* bsk = (const float*)d_in[13];
  const float* gamma = (const float*)d_in[14]; const float* beta = (const float*)d_in[15];

  const int N = in_sizes[0] / FDIM;
  const int E = in_sizes[1] / 2;
  const int* src = ei;
  const int* dst = ei + E;
  const int NK = N * NREL;

  // ---- workspace layout ----
  char* base = (char*)d_ws;
  size_t off = 0;
  auto alloc = [&](size_t bytes) -> char* {
    char* p = base + off;
    off += (bytes + 255) & ~(size_t)255;
    return p;
  };
  unsigned short* aggh = (unsigned short*)alloc((size_t)N * (NREL * FDIM) * 2);  // 76.8MB
  // q/k/v (all fp16) reuse the agg region after the RGCN GEMM consumes it:
  unsigned short* qbuf = aggh;
  unsigned short* kbuf = aggh + (size_t)N * FDIM;
  unsigned short* vbuf = aggh + 2 * (size_t)N * FDIM;
  unsigned short* xh   = (unsigned short*)alloc((size_t)N * FDIM * 2);
  unsigned short* hh   = (unsigned short*)alloc((size_t)N * FDIM * 2);
  unsigned short* btR  = (unsigned short*)alloc((size_t)896 * 128 * 2);
  unsigned short* btQ  = (unsigned short*)alloc((size_t)4 * 128 * 128 * 2);
  int* cnt6 = (int*)alloc((size_t)2 * NK * 4);
  int* cur  = cnt6 + NK;
  int* offs6 = (int*)alloc((size_t)(NK + 1) * 4);
  int* incl = (int*)alloc((size_t)NK * 4);
  int* part = (int*)alloc((size_t)512 * 4);
  int* csrc = (int*)alloc((size_t)E * 4);
  float* gsumB = (float*)alloc((size_t)32 * FDIM * 4);
  float* gsqB  = (float*)alloc((size_t)32 * FDIM * 4);
  float* ss    = (float*)alloc((size_t)2 * FDIM * 4);

  float* out = (float*)d_out;

  hipMemsetAsync(cnt6, 0, (size_t)2 * NK * sizeof(int), stream);
  hipMemsetAsync(gsumB, 0, (size_t)64 * FDIM * sizeof(float), stream);  // gsumB+gsqB

  // ---- conversions ----
  int n4 = N * FDIM / 4;
  cvt_x_kernel<<<(n4 + 255) / 256, 256, 0, stream>>>(x, xh, n4);
  cvt_wr_kernel<<<(896 * 128 + 255) / 256, 256, 0, stream>>>(rgcn_root, rgcn_w, btR);
  WPtrs wp; wp.W[0] = wq; wp.W[1] = wk; wp.W[2] = wv; wp.W[3] = wsk;
  cvt_wq_kernel<<<(4 * 128 * 128 + 255) / 256, 256, 0, stream>>>(wp, btQ);

  // ---- CSR build over (dst, rel) keys ----
  hist_kernel<<<(E + 255) / 256, 256, 0, stream>>>(dst, etype, cnt6, E);
  int nb = (NK + 1023) / 1024;
  scan1<<<nb, 1024, 0, stream>>>(cnt6, incl, part, NK);
  scan2<<<1, 64, 0, stream>>>(part, nb);
  scan3<<<(NK + 255) / 256, 256, 0, stream>>>(incl, part, offs6, NK);
  scatter_kernel<<<(E + 255) / 256, 256, 0, stream>>>(src, dst, etype, offs6, cur, csrc, E);

  const int nodeBlocks = (N + 3) / 4;
  const int gemmBlocks = (N + 63) / 64;

  // ---- RGCN: aggregate-first (fp16), then fused K=896 MFMA GEMM -> h (fp16) ----
  rgcn_agg<<<nodeBlocks, 256, 0, stream>>>(xh, offs6, csrc, aggh, N);

  GArgs g0 = {};
  g0.Ax = xh; g0.Aagg = aggh; g0.Bt = btR;
  g0.bias[0] = rgcn_bias;
  g0.h = hh; g0.M = N; g0.K = 896;
  gemm_mfma<0><<<dim3(gemmBlocks, 1, 1), 256, 0, stream>>>(g0);

  // ---- q,k,v,skip projections (z=4): q/k/v fp16 (q pre-scaled), skip f32 -> out ----
  GArgs g1 = {};
  g1.Ax = hh; g1.Bt = btQ;
  g1.bias[0] = bq; g1.bias[1] = bk; g1.bias[2] = bv; g1.bias[3] = bsk;
  g1.qh = qbuf; g1.kh = kbuf; g1.vh = vbuf; g1.sk = out;
  g1.M = N; g1.K = 128;
  gemm_mfma<1><<<dim3(gemmBlocks, 1, 4), 256, 0, stream>>>(g1);

  // ---- edge-softmax attention + fused BN-stats ----
  attn_kernel<<<nodeBlocks, 256, 0, stream>>>(qbuf, kbuf, vbuf, offs6, csrc, out,
                                              gsumB, gsqB, N);

  // ---- BatchNorm finalize + apply ----
  bn_final<<<1, 128, 0, stream>>>(gsumB, gsqB, gamma, beta, ss, N);
  long long total4 = (long long)N * FDIM / 4;
  bn_apply<<<(int)((total4 + 255) / 256), 256, 0, stream>>>(out, ss, total4);
}

// Round 18
// 300.512 us; speedup vs baseline: 1.2296x; 1.0157x over previous
//
#include <hip/hip_runtime.h>
#include <hip/hip_bf16.h>
#include <math.h>

#define FDIM 128
#define NREL 6

typedef _Float16 half8 __attribute__((ext_vector_type(8)));
typedef _Float16 h16x2 __attribute__((ext_vector_type(2)));
typedef float f32x4 __attribute__((ext_vector_type(4)));

#if __has_builtin(__builtin_amdgcn_fdot2)
#define FDOT2(A, B, C) __builtin_amdgcn_fdot2((A), (B), (C), false)
#else
#define FDOT2(A, B, C) ((float)(A)[0] * (float)(B)[0] + ((float)(A)[1] * (float)(B)[1] + (C)))
#endif

// ---------------- fp16 helpers ----------------------------------------------
static __device__ __forceinline__ unsigned short f2h(float f) {
  union { _Float16 h; unsigned short u; } p; p.h = (_Float16)f; return p.u;
}

// ---------------------------------------------------------------------------
// Fused dtype conversion: x (vec4), rgcn weights (transposed), qkvs weights
// (transposed) in ONE launch.
// ---------------------------------------------------------------------------
struct WPtrs { const float* W[4]; };

__global__ void cvt_all_kernel(const float* __restrict__ x, unsigned short* __restrict__ xh,
                               const float* __restrict__ root, const float* __restrict__ w,
                               unsigned short* __restrict__ btR,
                               WPtrs wp, unsigned short* __restrict__ btQ, int n4x) {
  int i = blockIdx.x * 256 + threadIdx.x;
  if (i < n4x) {
    float4 v = ((const float4*)x)[i];
    union { _Float16 h[4]; uint2 u; } p;
    p.h[0] = (_Float16)v.x; p.h[1] = (_Float16)v.y;
    p.h[2] = (_Float16)v.z; p.h[3] = (_Float16)v.w;
    ((uint2*)xh)[i] = p.u;
    return;
  }
  int j = i - n4x;
  if (j < 896 * 128) {
    int n = j / 896, kk = j - n * 896;
    float v = (kk < 128) ? root[kk * 128 + n] : w[(long long)(kk - 128) * 128 + n];
    btR[j] = f2h(v);
    return;
  }
  int q = j - 896 * 128;
  if (q < 4 * 128 * 128) {
    int z = q >> 14;
    int r = q & 16383;
    int n = r >> 7, kk = r & 127;
    btQ[q] = f2h(wp.W[z][kk * 128 + n]);
  }
}

// ---------------------------------------------------------------------------
// fp16 MFMA GEMM, tile 64(M) x 128(N), BK=64, 256 thr = 4 waves (2M x 2N).
// R11/R17-proven SPLIT structure. XOR-swizzled LDS; B pre-transposed.
// MODE1: z=1 -> k into kv[row*256 + col]; z=2 -> v into kv[row*256+128+col]
// (interleaved 512-B k|v rows for attn gather locality).
// ---------------------------------------------------------------------------
struct GArgs {
  const unsigned short* Ax;    // fp16 [M][128]  (x_h or h_h)
  const unsigned short* Aagg;  // fp16 [M][768]  (MODE0)
  const unsigned short* Bt;    // fp16 [z][128(n)][K]
  const float* bias[4];
  unsigned short* qh; unsigned short* kv; float* sk;  // MODE1
  unsigned short* h;                                  // MODE0
  int M, K;
};

template <int MODE>
__launch_bounds__(256)
__global__ void gemm_mfma(GArgs g) {
  __shared__ unsigned short Ah[64 * 64];    // [r][8 x 16B units], swizzled
  __shared__ unsigned short Bh[128 * 64];   // [n][8 x 16B units], swizzled
  const int tid = threadIdx.x;
  const int lane = tid & 63;
  const int wid = tid >> 6;
  const int wm = wid >> 1, wn = wid & 1;
  const int lr = lane & 15, lk = lane >> 4;
  const int m0 = blockIdx.x * 64;
  const int z = (MODE == 1) ? blockIdx.z : 0;
  const unsigned short* Bt = g.Bt + (long long)z * 128 * g.K;
  const int K = g.K;
  const int M = g.M;

  f32x4 acc[2][4];
#pragma unroll
  for (int a = 0; a < 2; ++a)
#pragma unroll
    for (int b = 0; b < 4; ++b) { acc[a][b][0] = 0.f; acc[a][b][1] = 0.f; acc[a][b][2] = 0.f; acc[a][b][3] = 0.f; }

  for (int k0 = 0; k0 < K; k0 += 64) {
    __syncthreads();
    // ---- stage A: 64 rows x 8 col16 units ----
#pragma unroll
    for (int p = 0; p < 2; ++p) {
      int idx = tid + 256 * p;
      int r = idx >> 3, c = idx & 7;
      int row = m0 + r; if (row > M - 1) row = M - 1;   // clamp tail (store guarded)
      const unsigned short* srcp;
      if (MODE == 0)
        srcp = (k0 < 128) ? (g.Ax + (long long)row * 128 + k0 + c * 8)
                          : (g.Aagg + (long long)row * 768 + (k0 - 128) + c * 8);
      else
        srcp = g.Ax + (long long)row * 128 + k0 + c * 8;
      uint4 u = *(const uint4*)srcp;
      ((uint4*)Ah)[r * 8 + (c ^ (r & 7))] = u;
    }
    // ---- stage B: 128 n-rows x 8 col16 units ----
#pragma unroll
    for (int p = 0; p < 4; ++p) {
      int idx = tid + 256 * p;
      int rn = idx >> 3, c = idx & 7;
      uint4 u = *(const uint4*)(Bt + (long long)rn * K + k0 + c * 8);
      ((uint4*)Bh)[rn * 8 + (c ^ (rn & 7))] = u;
    }
    __syncthreads();
    // ---- fragments + MFMA (2 K32 sub-steps) ----
#pragma unroll
    for (int ks = 0; ks < 2; ++ks) {
      half8 a[2], b[4];
#pragma unroll
      for (int fm = 0; fm < 2; ++fm) {
        int row = wm * 32 + fm * 16 + lr;
        a[fm] = *(const half8*)&((uint4*)Ah)[row * 8 + ((ks * 4 + lk) ^ (row & 7))];
      }
#pragma unroll
      for (int fn = 0; fn < 4; ++fn) {
        int col = wn * 64 + fn * 16 + lr;
        b[fn] = *(const half8*)&((uint4*)Bh)[col * 8 + ((ks * 4 + lk) ^ (col & 7))];
      }
#pragma unroll
      for (int fm = 0; fm < 2; ++fm)
#pragma unroll
        for (int fn = 0; fn < 4; ++fn)
          acc[fm][fn] = __builtin_amdgcn_mfma_f32_16x16x32_f16(a[fm], b[fn], acc[fm][fn], 0, 0, 0);
    }
  }

  // ---- epilogue ----
  const float CF = 0.08838834764831845f * 1.4426950408889634f;  // 1/sqrt(128)*log2(e)
  const float* bias = (MODE == 0) ? g.bias[0] : g.bias[z];
#pragma unroll
  for (int fm = 0; fm < 2; ++fm) {
#pragma unroll
    for (int fn = 0; fn < 4; ++fn) {
      int col = wn * 64 + fn * 16 + lr;
      float bv = bias[col];
#pragma unroll
      for (int j = 0; j < 4; ++j) {
        int row = m0 + wm * 32 + fm * 16 + lk * 4 + j;
        if (row < M) {
          float vv = acc[fm][fn][j] + bv;
          if (MODE == 0) {
            g.h[(long long)row * 128 + col] = f2h(vv);
          } else {
            if (z == 0) g.qh[(long long)row * 128 + col] = f2h(vv * CF);
            else if (z == 1) g.kv[(long long)row * 256 + col] = f2h(vv);
            else if (z == 2) g.kv[(long long)row * 256 + 128 + col] = f2h(vv);
            else g.sk[(long long)row * 128 + col] = vv;
          }
        }
      }
    }
  }
}

// ---------------------------------------------------------------------------
// CSR construction over (dst, rel) keys; csrc stores plain src indices.
// ---------------------------------------------------------------------------
__global__ void hist_kernel(const int* __restrict__ dst, const int* __restrict__ etype,
                            int* __restrict__ cnt, int E) {
  int e = blockIdx.x * blockDim.x + threadIdx.x;
  if (e < E) atomicAdd(&cnt[dst[e] * NREL + etype[e]], 1);
}

__launch_bounds__(1024)
__global__ void scan1(const int* __restrict__ deg, int* __restrict__ incl,
                      int* __restrict__ part, int n) {
  __shared__ int sh[1024];
  int tid = threadIdx.x;
  int i = blockIdx.x * 1024 + tid;
  sh[tid] = (i < n) ? deg[i] : 0;
  __syncthreads();
  for (int o = 1; o < 1024; o <<= 1) {
    int t = (tid >= o) ? sh[tid - o] : 0;
    __syncthreads();
    sh[tid] += t;
    __syncthreads();
  }
  if (i < n) incl[i] = sh[tid];
  if (tid == 1023) part[blockIdx.x] = sh[1023];
}

__global__ void scan2(int* part, int nb) {
  int lane = threadIdx.x;  // 64 threads
  int run = 0;
  for (int b0 = 0; b0 < nb; b0 += 64) {
    int i = b0 + lane;
    int orig = (i < nb) ? part[i] : 0;
    int v = orig;
#pragma unroll
    for (int o = 1; o < 64; o <<= 1) {
      int t = __shfl_up(v, o);
      if (lane >= o) v += t;
    }
    if (i < nb) part[i] = run + v - orig;  // exclusive
    run += __shfl(v, 63);
  }
}

__global__ void scan3(const int* __restrict__ incl, const int* __restrict__ part,
                      int* __restrict__ offs, int n) {
  int i = blockIdx.x * blockDim.x + threadIdx.x;
  if (i < n) {
    offs[i + 1] = incl[i] + part[i >> 10];
    if (i == 0) offs[0] = 0;
  }
}

__global__ void scatter_kernel(const int* __restrict__ src, const int* __restrict__ dst,
                               const int* __restrict__ etype, const int* __restrict__ offs6,
                               int* __restrict__ cur, int* __restrict__ csrc, int E) {
  int e = blockIdx.x * blockDim.x + threadIdx.x;
  if (e < E) {
    int key = dst[e] * NREL + etype[e];
    int p = offs6[key] + atomicAdd(&cur[key], 1);
    csrc[p] = src[e];
  }
}

// ---------------------------------------------------------------------------
// RGCN aggregation, one WAVE per node, rel-sorted edges, PREFIX SNAPSHOT.
// 16-deep unrolled gather loop (16 loads in flight; gather-latency-bound).
// ---------------------------------------------------------------------------
__launch_bounds__(256)
__global__ void rgcn_agg(const unsigned short* __restrict__ xh, const int* __restrict__ offs6,
                         const int* __restrict__ csrc,
                         unsigned short* __restrict__ aggh, int N) {
  int node = blockIdx.x * 4 + (threadIdx.x >> 6);
  if (node >= N) return;
  int lane = threadIdx.x & 63;
  const char* xc = (const char*)xh;
  const int* bp = offs6 + node * NREL;
  const int b0 = bp[0];
  int bn0 = bp[1], bn1 = bp[2], bn2 = bp[3], bn3 = bp[4], bn4 = bp[5], bn5 = bp[6];
  const int b6 = bn5;
  unsigned* ap = (unsigned*)(aggh + (long long)node * (NREL * FDIM)) + lane;

  float tx = 0.f, ty = 0.f;
  float px = 0.f, py = 0.f;
  int bprev = b0, snaps = 0;

#define FLUSH(EPOS)                                                          \
  while (snaps < NREL && bn0 == (EPOS)) {                                    \
    int cnt_ = (EPOS) - bprev;                                               \
    float inv_ = cnt_ ? 1.f / (float)cnt_ : 0.f;                             \
    union { _Float16 h[2]; unsigned u; } pk_;                                \
    pk_.h[0] = (_Float16)((tx - px) * inv_);                                 \
    pk_.h[1] = (_Float16)((ty - py) * inv_);                                 \
    *ap = pk_.u; ap += 64;                                                   \
    px = tx; py = ty; bprev = (EPOS); ++snaps;                               \
    bn0 = bn1; bn1 = bn2; bn2 = bn3; bn3 = bn4; bn4 = bn5;                   \
  }

#define EAT(XU)                                                              \
  {                                                                          \
    union { unsigned u; _Float16 h[2]; } c_; c_.u = (XU);                    \
    tx += (float)c_.h[0]; ty += (float)c_.h[1];                              \
  }

  FLUSH(b0)
  int e = b0;
  for (; e + 16 <= b6; e += 16) {
    unsigned xv[16];
#pragma unroll
    for (int t = 0; t < 16; ++t)
      xv[t] = ((const unsigned*)(xc + ((long long)csrc[e + t] << 8)))[lane];
    EAT(xv[0])  FLUSH(e + 1)   EAT(xv[1])  FLUSH(e + 2)
    EAT(xv[2])  FLUSH(e + 3)   EAT(xv[3])  FLUSH(e + 4)
    EAT(xv[4])  FLUSH(e + 5)   EAT(xv[5])  FLUSH(e + 6)
    EAT(xv[6])  FLUSH(e + 7)   EAT(xv[7])  FLUSH(e + 8)
    EAT(xv[8])  FLUSH(e + 9)   EAT(xv[9])  FLUSH(e + 10)
    EAT(xv[10]) FLUSH(e + 11)  EAT(xv[11]) FLUSH(e + 12)
    EAT(xv[12]) FLUSH(e + 13)  EAT(xv[13]) FLUSH(e + 14)
    EAT(xv[14]) FLUSH(e + 15)  EAT(xv[15]) FLUSH(e + 16)
  }
  for (; e + 4 <= b6; e += 4) {
    unsigned y0 = ((const unsigned*)(xc + ((long long)csrc[e + 0] << 8)))[lane];
    unsigned y1 = ((const unsigned*)(xc + ((long long)csrc[e + 1] << 8)))[lane];
    unsigned y2 = ((const unsigned*)(xc + ((long long)csrc[e + 2] << 8)))[lane];
    unsigned y3 = ((const unsigned*)(xc + ((long long)csrc[e + 3] << 8)))[lane];
    EAT(y0) FLUSH(e + 1) EAT(y1) FLUSH(e + 2)
    EAT(y2) FLUSH(e + 3) EAT(y3) FLUSH(e + 4)
  }
  for (; e < b6; ++e) {
    unsigned xv = ((const unsigned*)(xc + ((long long)csrc[e] << 8)))[lane];
    EAT(xv) FLUSH(e + 1)
  }
#undef EAT
#undef FLUSH
}

// ---------------------------------------------------------------------------
// TransformerConv edge-softmax + fused BN-stats. One WAVE per node, QUAD-edge
// processing. k|v interleaved 512-B rows (one contiguous block per edge).
// V-accumulation in packed fp16 (v_pk_fma_f16): acc bounded by deg*max|v|,
// well inside fp16 range; saves ~half the accumulation VALU ops.
// ---------------------------------------------------------------------------
__launch_bounds__(256)
__global__ void attn_kernel(const unsigned short* __restrict__ qh,
                            const unsigned short* __restrict__ kv,
                            const int* __restrict__ offs6, const int* __restrict__ csrc,
                            float* __restrict__ out,
                            float* __restrict__ gsumB, float* __restrict__ gsqB, int N) {
  __shared__ float bsum[4][FDIM];
  __shared__ float bsq[4][FDIM];
  int wv = threadIdx.x >> 6;
  int node = blockIdx.x * 4 + wv;
  int lane = threadIdx.x & 63;
  bool active = (node < N);
  int start = 0, end = 0;
  if (active) { start = offs6[node * NREL]; end = offs6[node * NREL + NREL]; }
  int deg = end - start;

  const int g16 = lane >> 4;
  const int f = lane & 15;
  const char* kvc = (const char*)kv;

  union U4 { uint4 u; h16x2 h[4]; };
  U4 qf;
  if (active) qf.u = *(const uint4*)(qh + (long long)node * FDIM + f * 8);

  float m = -INFINITY, den = 0.f;
  h16x2 accv; accv[0] = (_Float16)0.f; accv[1] = (_Float16)0.f;

#define LOADQ(E0, KU, V0, V1, V2, V3)                                        \
  {                                                                          \
    long long S0 = (long long)csrc[(E0) + (g16 ^ 0)] << 9;                   \
    long long S1 = (long long)csrc[(E0) + (g16 ^ 1)] << 9;                   \
    long long S2 = (long long)csrc[(E0) + (g16 ^ 2)] << 9;                   \
    long long S3 = (long long)csrc[(E0) + (g16 ^ 3)] << 9;                   \
    KU = *(const uint4*)(kvc + S0 + f * 16);                                 \
    V0 = *(const unsigned*)(kvc + S0 + 256 + lane * 4);                      \
    V1 = *(const unsigned*)(kvc + S1 + 256 + lane * 4);                      \
    V2 = *(const unsigned*)(kvc + S2 + 256 + lane * 4);                      \
    V3 = *(const unsigned*)(kvc + S3 + 256 + lane * 4);                      \
  }

#define PROCESS(KU, V0, V1, V2, V3, MASKED, M0, M1, M2, M3)                  \
  {                                                                          \
    U4 kf; kf.u = KU;                                                        \
    float pd = FDOT2(qf.h[0], kf.h[0], 0.f);                                 \
    pd = FDOT2(qf.h[1], kf.h[1], pd);                                        \
    pd = FDOT2(qf.h[2], kf.h[2], pd);                                        \
    pd = FDOT2(qf.h[3], kf.h[3], pd);                                        \
    pd += __shfl_xor(pd, 1);  pd += __shfl_xor(pd, 2);                       \
    pd += __shfl_xor(pd, 4);  pd += __shfl_xor(pd, 8);                       \
    float sc0 = pd;                                                          \
    float sc1 = __shfl_xor(pd, 16);                                          \
    float sc2 = __shfl_xor(pd, 32);                                          \
    float sc3 = __shfl_xor(pd, 48);                                          \
    if (MASKED) {                                                            \
      if (!(M0)) sc0 = -INFINITY;                                            \
      if (!(M1)) sc1 = -INFINITY;                                            \
      if (!(M2)) sc2 = -INFINITY;                                            \
      if (!(M3)) sc3 = -INFINITY;                                            \
    }                                                                        \
    float mx = fmaxf(fmaxf(sc0, sc1), fmaxf(sc2, sc3));                      \
    float mn = fmaxf(m, mx);                                                 \
    float scl = exp2f(m - mn);                                               \
    float a0 = exp2f(sc0 - mn), a1 = exp2f(sc1 - mn);                        \
    float a2 = exp2f(sc2 - mn), a3 = exp2f(sc3 - mn);                        \
    den = den * scl + ((a0 + a1) + (a2 + a3));                               \
    union { unsigned u; h16x2 h; } w0, w1, w2, w3;                           \
    w0.u = V0; w1.u = V1; w2.u = V2; w3.u = V3;                              \
    h16x2 sclh; sclh[0] = (_Float16)scl; sclh[1] = sclh[0];                  \
    h16x2 ah; accv = accv * sclh;                                            \
    ah[0] = (_Float16)a0; ah[1] = ah[0]; accv += ah * w0.h;                  \
    ah[0] = (_Float16)a1; ah[1] = ah[0]; accv += ah * w1.h;                  \
    ah[0] = (_Float16)a2; ah[1] = ah[0]; accv += ah * w2.h;                  \
    ah[0] = (_Float16)a3; ah[1] = ah[0]; accv += ah * w3.h;                  \
    m = mn;                                                                  \
  }

  if (deg > 0) {
    int nfull4 = deg & ~3;
    int e = start;
    if (nfull4 > 0) {
      uint4 kA; unsigned vA0, vA1, vA2, vA3;
      LOADQ(e, kA, vA0, vA1, vA2, vA3)
      for (; e < start + nfull4; e += 4) {
        uint4 kB; unsigned vB0, vB1, vB2, vB3;
        bool more = (e + 4 < start + nfull4);
        if (more) LOADQ(e + 4, kB, vB0, vB1, vB2, vB3)
        PROCESS(kA, vA0, vA1, vA2, vA3, false, 1, 1, 1, 1)
        if (more) { kA = kB; vA0 = vB0; vA1 = vB1; vA2 = vB2; vA3 = vB3; }
      }
    }
    int rem = deg & 3;
    if (rem) {
      int e0 = start + nfull4;
      int j0 = g16 ^ 0, j1 = g16 ^ 1, j2 = g16 ^ 2, j3 = g16 ^ 3;
      long long sT0 = (long long)csrc[e0 + (j0 < rem ? j0 : 0)] << 9;
      long long sT1 = (long long)csrc[e0 + (j1 < rem ? j1 : 0)] << 9;
      long long sT2 = (long long)csrc[e0 + (j2 < rem ? j2 : 0)] << 9;
      long long sT3 = (long long)csrc[e0 + (j3 < rem ? j3 : 0)] << 9;
      uint4 kT = *(const uint4*)(kvc + sT0 + f * 16);
      unsigned vT0 = *(const unsigned*)(kvc + sT0 + 256 + lane * 4);
      unsigned vT1 = *(const unsigned*)(kvc + sT1 + 256 + lane * 4);
      unsigned vT2 = *(const unsigned*)(kvc + sT2 + 256 + lane * 4);
      unsigned vT3 = *(const unsigned*)(kvc + sT3 + 256 + lane * 4);
      PROCESS(kT, vT0, vT1, vT2, vT3, true, j0 < rem, j1 < rem, j2 < rem, j3 < rem)
    }
  }
#undef LOADQ
#undef PROCESS

  float2 o = make_float2(0.f, 0.f);
  if (active) {
    float2* op = (float2*)(out + (long long)node * FDIM);
    o = op[lane];
    if (deg > 0) {
      float inv = 1.f / den;
      o.x += (float)accv[0] * inv;
      o.y += (float)accv[1] * inv;
      op[lane] = o;
    }
  }

  // ---- fused BN-stats: o is the final pre-BN value of this node ----
  ((float2*)bsum[wv])[lane] = make_float2(o.x, o.y);
  ((float2*)bsq[wv])[lane]  = make_float2(o.x * o.x, o.y * o.y);
  __syncthreads();
  if (threadIdx.x < FDIM) {
    int d = threadIdx.x;
    float s  = bsum[0][d] + bsum[1][d] + bsum[2][d] + bsum[3][d];
    float q2 = bsq[0][d]  + bsq[1][d]  + bsq[2][d]  + bsq[3][d];
    int bucket = blockIdx.x & 31;
    atomicAdd(&gsumB[bucket * FDIM + d], s);
    atomicAdd(&gsqB[bucket * FDIM + d], q2);
  }
}

// ---------------------------------------------------------------------------
// BatchNorm finalize (reduce 32 buckets) + LeakyReLU apply
// ---------------------------------------------------------------------------
__global__ void bn_final(const float* __restrict__ gsumB, const float* __restrict__ gsqB,
                         const float* __restrict__ gamma, const float* __restrict__ beta,
                         float* __restrict__ ss, int N) {
  int d = threadIdx.x;
  if (d < FDIM) {
    float s = 0.f, q = 0.f;
    for (int b = 0; b < 32; ++b) { s += gsumB[b * FDIM + d]; q += gsqB[b * FDIM + d]; }
    float mean = s / (float)N;
    float var = q / (float)N - mean * mean;
    var = fmaxf(var, 0.f);
    float sc = gamma[d] * rsqrtf(var + 1e-5f);
    ss[d] = sc;
    ss[FDIM + d] = beta[d] - mean * sc;
  }
}

__global__ void bn_apply(float* __restrict__ x, const float* __restrict__ ss, long long total4) {
  long long i = (long long)blockIdx.x * blockDim.x + threadIdx.x;
  if (i < total4) {
    int d0 = (int)((i * 4) & (FDIM - 1));
    float4 vv = ((const float4*)x)[i];
    float y0 = ss[d0 + 0] * vv.x + ss[FDIM + d0 + 0];
    float y1 = ss[d0 + 1] * vv.y + ss[FDIM + d0 + 1];
    float y2 = ss[d0 + 2] * vv.z + ss[FDIM + d0 + 2];
    float y3 = ss[d0 + 3] * vv.w + ss[FDIM + d0 + 3];
    vv.x = (y0 > 0.f) ? y0 : 0.01f * y0;
    vv.y = (y1 > 0.f) ? y1 : 0.01f * y1;
    vv.z = (y2 > 0.f) ? y2 : 0.01f * y2;
    vv.w = (y3 > 0.f) ? y3 : 0.01f * y3;
    ((float4*)x)[i] = vv;
  }
}

// ---------------------------------------------------------------------------
// Launcher
// ---------------------------------------------------------------------------
extern "C" void kernel_launch(void* const* d_in, const int* in_sizes, int n_in,
                              void* d_out, int out_size, void* d_ws, size_t ws_size,
                              hipStream_t stream) {
  const float* x         = (const float*)d_in[0];
  const int*   ei        = (const int*)d_in[1];
  const int*   etype     = (const int*)d_in[2];
  const float* rgcn_w    = (const float*)d_in[3];
  const float* rgcn_root = (const float*)d_in[4];
  const float* rgcn_bias = (const float*)d_in[5];
  const float* wq = (const float*)d_in[6];  const float* bq = (const float*)d_in[7];
  const float* wk = (const float*)d_in[8];  const float* bk = (const float*)d_in[9];
  const float* wv = (const float*)d_in[10]; const float* bv = (const float*)d_in[11];
  const float* wsk = (const float*)d_in[12]; const float* bsk = (const float*)d_in[13];
  const float* gamma = (const float*)d_in[14]; const float* beta = (const float*)d_in[15];

  const int N = in_sizes[0] / FDIM;
  const int E = in_sizes[1] / 2;
  const int* src = ei;
  const int* dst = ei + E;
  const int NK = N * NREL;

  // ---- workspace layout ----
  char* base = (char*)d_ws;
  size_t off = 0;
  auto alloc = [&](size_t bytes) -> char* {
    char* p = base + off;
    off += (bytes + 255) & ~(size_t)255;
    return p;
  };
  unsigned short* aggh = (unsigned short*)alloc((size_t)N * (NREL * FDIM) * 2);  // 76.8MB
  // q + interleaved k|v reuse the agg region after the RGCN GEMM consumes it:
  unsigned short* qbuf  = aggh;                               // N*128 fp16
  unsigned short* kvbuf = aggh + (size_t)N * FDIM;            // N*256 fp16 (k|v rows)
  unsigned short* xh   = (unsigned short*)alloc((size_t)N * FDIM * 2);
  unsigned short* hh   = (unsigned short*)alloc((size_t)N * FDIM * 2);
  unsigned short* btR  = (unsigned short*)alloc((size_t)896 * 128 * 2);
  unsigned short* btQ  = (unsigned short*)alloc((size_t)4 * 128 * 128 * 2);
  int* cnt6 = (int*)alloc((size_t)2 * NK * 4);
  int* cur  = cnt6 + NK;
  int* offs6 = (int*)alloc((size_t)(NK + 1) * 4);
  int* incl = (int*)alloc((size_t)NK * 4);
  int* part = (int*)alloc((size_t)512 * 4);
  int* csrc = (int*)alloc((size_t)E * 4);
  float* gsumB = (float*)alloc((size_t)32 * FDIM * 4);
  float* gsqB  = (float*)alloc((size_t)32 * FDIM * 4);
  float* ss    = (float*)alloc((size_t)2 * FDIM * 4);

  float* out = (float*)d_out;

  hipMemsetAsync(cnt6, 0, (size_t)2 * NK * sizeof(int), stream);
  hipMemsetAsync(gsumB, 0, (size_t)64 * FDIM * sizeof(float), stream);  // gsumB+gsqB

  // ---- fused conversions (one launch) ----
  int n4x = N * FDIM / 4;
  WPtrs wp; wp.W[0] = wq; wp.W[1] = wk; wp.W[2] = wv; wp.W[3] = wsk;
  int cvtTotal = n4x + 896 * 128 + 4 * 128 * 128;
  cvt_all_kernel<<<(cvtTotal + 255) / 256, 256, 0, stream>>>(
      x, xh, rgcn_root, rgcn_w, btR, wp, btQ, n4x);

  // ---- CSR build over (dst, rel) keys ----
  hist_kernel<<<(E + 255) / 256, 256, 0, stream>>>(dst, etype, cnt6, E);
  int nb = (NK + 1023) / 1024;
  scan1<<<nb, 1024, 0, stream>>>(cnt6, incl, part, NK);
  scan2<<<1, 64, 0, stream>>>(part, nb);
  scan3<<<(NK + 255) / 256, 256, 0, stream>>>(incl, part, offs6, NK);
  scatter_kernel<<<(E + 255) / 256, 256, 0, stream>>>(src, dst, etype, offs6, cur, csrc, E);

  const int nodeBlocks = (N + 3) / 4;
  const int gemmBlocks = (N + 63) / 64;

  // ---- RGCN: aggregate-first (fp16), then K=896 MFMA GEMM -> h (fp16) ----
  rgcn_agg<<<nodeBlocks, 256, 0, stream>>>(xh, offs6, csrc, aggh, N);

  GArgs g0 = {};
  g0.Ax = xh; g0.Aagg = aggh; g0.Bt = btR;
  g0.bias[0] = rgcn_bias;
  g0.h = hh; g0.M = N; g0.K = 896;
  gemm_mfma<0><<<dim3(gemmBlocks, 1, 1), 256, 0, stream>>>(g0);

  // ---- q,k,v,skip projections (z=4): q fp16 pre-scaled, k|v interleaved ----
  GArgs g1 = {};
  g1.Ax = hh; g1.Bt = btQ;
  g1.bias[0] = bq; g1.bias[1] = bk; g1.bias[2] = bv; g1.bias[3] = bsk;
  g1.qh = qbuf; g1.kv = kvbuf; g1.sk = out;
  g1.M = N; g1.K = 128;
  gemm_mfma<1><<<dim3(gemmBlocks, 1, 4), 256, 0, stream>>>(g1);

  // ---- edge-softmax attention + fused BN-stats ----
  attn_kernel<<<nodeBlocks, 256, 0, stream>>>(qbuf, kvbuf, offs6, csrc, out,
                                              gsumB, gsqB, N);

  // ---- BatchNorm finalize + apply ----
  bn_final<<<1, 128, 0, stream>>>(gsumB, gsqB, gamma, beta, ss, N);
  long long total4 = (long long)N * FDIM / 4;
  bn_apply<<<(int)((total4 + 255) / 256), 256, 0, stream>>>(out, ss, total4);
}